// Round 10
// baseline (1006.659 us; speedup 1.0000x reference)
//
#include <hip/hip_runtime.h>

#define N_NODES 50000
#define N_EDGES 1600000
#define E_TOT   (N_EDGES + N_NODES)   // 1,650,000 incl. self-loops
#define IN_CH   128
#define C1      64                    // heads(2) * hid(32)
#define OUT_CH  128
#define N_GRAPHS 64
#define NEG_SLOPE 0.2f

#define BSH   7                        // 128 dsts per bucket
#define NBUCK ((N_NODES + 127) / 128)  // 391
#define BCAP  5120                     // per-bucket region cap (mean 4220, ~14 sigma)
#define CHUNK 8192                     // edges per k_bin workgroup

__device__ __forceinline__ float elu_f(float v) {
    return v > 0.f ? v : (__expf(v) - 1.f);
}
__device__ __forceinline__ unsigned short f2bf(float f) {   // RNE
    unsigned u = __float_as_uint(f);
    return (unsigned short)((u + 0x7FFFu + ((u >> 16) & 1u)) >> 16);
}
__device__ __forceinline__ float bf_lo(unsigned u) { return __uint_as_float(u << 16); }
__device__ __forceinline__ float bf_hi(unsigned u) { return __uint_as_float(u & 0xFFFF0000u); }

// ---------------- GEMM1: xl1(bf16) = x @ W1, fused per-head attention dots ---
__global__ __launch_bounds__(256) void k_gemm1(
    const float* __restrict__ x, const float* __restrict__ W1,
    const float* __restrict__ att_s, const float* __restrict__ att_d,
    unsigned short* __restrict__ xl1, float* __restrict__ a_s, float* __restrict__ a_d)
{
    __shared__ float Ws[IN_CH * C1];   // 32 KB
    __shared__ float xr[4][IN_CH];
    const int t = threadIdx.x, wave = t >> 6, lane = t & 63;
    for (int i = t; i < IN_CH * C1; i += 256) Ws[i] = W1[i];
    __syncthreads();
    const float as_c = att_s[lane], ad_c = att_d[lane];
    const int ngroups = N_NODES / 4;   // 12500, exact
    for (int g = blockIdx.x; g < ngroups; g += gridDim.x) {
        const int r = g * 4 + wave;
        xr[wave][lane]      = x[r * IN_CH + lane];
        xr[wave][lane + 64] = x[r * IN_CH + lane + 64];
        __syncthreads();
        float acc = 0.f;
        #pragma unroll
        for (int k4 = 0; k4 < IN_CH / 4; ++k4) {
            float4 xv = *(const float4*)&xr[wave][k4 * 4];
            acc = fmaf(xv.x, Ws[(k4*4+0)*C1 + lane], acc);
            acc = fmaf(xv.y, Ws[(k4*4+1)*C1 + lane], acc);
            acc = fmaf(xv.z, Ws[(k4*4+2)*C1 + lane], acc);
            acc = fmaf(xv.w, Ws[(k4*4+3)*C1 + lane], acc);
        }
        xl1[r * C1 + lane] = f2bf(acc);
        float ps = acc * as_c, pd = acc * ad_c;
        #pragma unroll
        for (int m = 16; m >= 1; m >>= 1) {
            ps += __shfl_xor(ps, m, 32);
            pd += __shfl_xor(pd, m, 32);
        }
        if ((lane & 31) == 0) {
            a_s[r * 2 + (lane >> 5)] = ps;
            a_d[r * 2 + (lane >> 5)] = pd;
        }
        __syncthreads();
    }
}

// ---------------- pass 1: LDS-staged binning by dst>>7 ----------------------
__global__ __launch_bounds__(256) void k_bin(
    const int* __restrict__ ei, int* __restrict__ gcur, unsigned* __restrict__ bbuf)
{
    __shared__ int cnt[512];               // counts -> inclusive scan (512 >= NBUCK)
    __shared__ int base[NBUCK];
    __shared__ int cnt2[NBUCK];
    __shared__ int gpos[NBUCK];
    __shared__ unsigned stage[CHUNK];      // 32 KB
    __shared__ unsigned short bof[CHUNK];  // 16 KB
    const int t = threadIdx.x;
    const long long e0 = (long long)blockIdx.x * CHUNK;
    const int nE = (int)min((long long)CHUNK, (long long)E_TOT - e0);

    cnt[t] = 0; cnt[t + 256] = 0;
    for (int b = t; b < NBUCK; b += 256) cnt2[b] = 0;
    __syncthreads();

    const int per = CHUNK / 256;           // 32
    int myb[per]; unsigned mye[per];
    #pragma unroll
    for (int i = 0; i < per; ++i) {
        int idx = t + 256 * i;
        myb[i] = -1;
        if (idx < nE) {
            long long e = e0 + idx;
            int s, d;
            if (e < N_EDGES) { s = ei[e]; d = ei[N_EDGES + e]; }
            else             { s = d = (int)(e - N_EDGES); }
            myb[i] = d >> BSH;
            mye[i] = ((unsigned)(d & 127) << 17) | (unsigned)s;
            atomicAdd(&cnt[myb[i]], 1);
        }
    }
    __syncthreads();
    for (int ofs = 1; ofs < 512; ofs <<= 1) {
        int v0 = (t >= ofs) ? cnt[t - ofs] : 0;
        int v1 = cnt[t + 256 - ofs];
        __syncthreads();
        cnt[t] += v0; cnt[t + 256] += v1;
        __syncthreads();
    }
    for (int b = t; b < NBUCK; b += 256) {
        base[b] = (b == 0) ? 0 : cnt[b - 1];
        int c = cnt[b] - base[b];
        gpos[b] = (c > 0) ? atomicAdd(&gcur[b], c) : 0;
    }
    __syncthreads();
    #pragma unroll
    for (int i = 0; i < per; ++i) {
        if (myb[i] >= 0) {
            int slot = base[myb[i]] + atomicAdd(&cnt2[myb[i]], 1);
            stage[slot] = mye[i];
            bof[slot] = (unsigned short)myb[i];
        }
    }
    __syncthreads();
    for (int i = t; i < nE; i += 256) {
        int b = bof[i];
        int pos = gpos[b] + (i - base[b]);
        if (pos < BCAP)
            bbuf[(size_t)b * BCAP + pos] = stage[i];
    }
}

// ---------------- pass 2: per-bucket counting sort, emits beg/end -----------
__global__ __launch_bounds__(256) void k_bsort(
    const int* __restrict__ gcur, unsigned* __restrict__ bbuf,
    int* __restrict__ beg, int* __restrict__ end)
{
    __shared__ unsigned est[BCAP];   // 20 KB
    __shared__ unsigned sst[BCAP];   // 20 KB
    __shared__ int c[128], lbase[128], c2[128];
    const int b = blockIdx.x, t = threadIdx.x;
    const int n = min(gcur[b], BCAP);
    unsigned* reg = bbuf + (size_t)b * BCAP;
    for (int i = t; i < n; i += 256) est[i] = reg[i];
    if (t < 128) { c[t] = 0; c2[t] = 0; }
    __syncthreads();
    for (int i = t; i < n; i += 256) atomicAdd(&c[est[i] >> 17], 1);
    __syncthreads();
    for (int ofs = 1; ofs < 128; ofs <<= 1) {
        int v = (t < 128 && t >= ofs) ? c[t - ofs] : 0;
        __syncthreads();
        if (t < 128) c[t] += v;
        __syncthreads();
    }
    if (t < 128) {
        lbase[t] = (t == 0) ? 0 : c[t - 1];
        int dst = (b << BSH) + t;
        if (dst < N_NODES) {
            beg[dst] = b * BCAP + lbase[t];
            end[dst] = b * BCAP + c[t];
        }
    }
    __syncthreads();
    for (int i = t; i < n; i += 256) {
        unsigned v = est[i];
        int dl = (int)(v >> 17);
        int pos = lbase[dl] + atomicAdd(&c2[dl], 1);
        sst[pos] = v & 0x1FFFFu;
    }
    __syncthreads();
    for (int i = t; i < n; i += 256) reg[i] = sst[i];
}

// ------- fused layer-1 attention + GEMM2: one wave per dst -------------------
// Phase A: GAT softmax-aggregate (CH=64, H=2), 8 lanes/edge, 4x8 edges/iter.
// Phase B: h = elu(row + b1); xl2 = h @ W2 (bf16 W2 in LDS); fused a_s2/a_d2.
// NOTE: all __shfl executed wave-uniformly (ds_bpermute reads 0 from
// exec-inactive source lanes — divergent shuffles corrupt the weights).
__global__ __launch_bounds__(256) void k_attn1g2(
    const int* __restrict__ beg_a, const int* __restrict__ end_a,
    const unsigned* __restrict__ csr,
    const float* __restrict__ a_s, const float* __restrict__ a_d,
    const unsigned short* __restrict__ xl,
    const float* __restrict__ b1, const float* __restrict__ W2,
    const float* __restrict__ att_s2, const float* __restrict__ att_d2,
    unsigned* __restrict__ xl2p,          // bf16x2-packed xl2, [N][64] words
    float* __restrict__ a_s2, float* __restrict__ a_d2)
{
    __shared__ unsigned W2p[C1 * 64];     // 16 KB: row k, col-pair p -> (2p,2p+1)
    __shared__ float hbuf[4][C1];         // 1 KB per-wave h rows
    const int t = threadIdx.x, wave = t >> 6, lane = t & 63;
    for (int i = t; i < C1 * 64; i += 256) {
        int k = i >> 6, p = i & 63;
        unsigned lo = f2bf(W2[k * 128 + 2 * p]);
        unsigned hi = f2bf(W2[k * 128 + 2 * p + 1]);
        W2p[i] = lo | (hi << 16);
    }
    const int dst = blockIdx.x * 4 + wave;           // grid = 12500
    const int beg = beg_a[dst], end = end_a[dst];
    const float ad0 = a_d[dst * 2], ad1 = a_d[dst * 2 + 1];
    const int li = lane & 7, sub = lane >> 3;
    const float4 b1a = *(const float4*)&b1[li * 8];
    const float4 b1b = *(const float4*)&b1[li * 8 + 4];
    const float2 as2c = *(const float2*)&att_s2[2 * lane];
    const float2 ad2c = *(const float2*)&att_d2[2 * lane];
    __syncthreads();

    float acc[8];
    #pragma unroll
    for (int i = 0; i < 8; ++i) acc[i] = 0.f;
    float ws0 = 0.f, ws1 = 0.f;
    for (int base = beg; base < end; base += 64) {
        const int cnt = min(64, end - base);
        int s = 0; float w0 = 0.f, w1 = 0.f;
        if (base + lane < end) {
            s = (int)csr[base + lane];
            float e0 = a_s[s * 2] + ad0;     e0 = e0 > 0.f ? e0 : NEG_SLOPE * e0;
            float e1 = a_s[s * 2 + 1] + ad1; e1 = e1 > 0.f ? e1 : NEG_SLOPE * e1;
            w0 = __expf(e0);
            w1 = __expf(e1);
        }
        ws0 += w0; ws1 += w1;
        for (int k = 0; k < cnt; k += 32) {      // 4 batches of 8 edges
            const int ia = k + sub, ib = k + 8 + sub, ic = k + 16 + sub, id = k + 24 + sub;
            // uniform shuffles, per-lane select AFTER (exec-mask safety)
            int   sa  = __shfl(s, ia, 64);       // idx>=cnt -> w=0,s=0: harmless
            float wa0 = __shfl(w0, ia, 64);
            float wa1 = __shfl(w1, ia, 64);
            int   sb  = __shfl(s, ib, 64);
            float wb0 = __shfl(w0, ib, 64);
            float wb1 = __shfl(w1, ib, 64);
            int   sc  = __shfl(s, ic, 64);
            float wc0 = __shfl(w0, ic, 64);
            float wc1 = __shfl(w1, ic, 64);
            int   sd  = __shfl(s, id, 64);
            float wd0 = __shfl(w0, id, 64);
            float wd1 = __shfl(w1, id, 64);
            float wa = (li < 4) ? wa0 : wa1;
            float wb = (li < 4) ? wb0 : wb1;
            float wc = (li < 4) ? wc0 : wc1;
            float wd = (li < 4) ? wd0 : wd1;
            uint4 va = *(const uint4*)&xl[(size_t)sa * 64 + li * 8];
            uint4 vb = *(const uint4*)&xl[(size_t)sb * 64 + li * 8];
            uint4 vc = *(const uint4*)&xl[(size_t)sc * 64 + li * 8];
            uint4 vd = *(const uint4*)&xl[(size_t)sd * 64 + li * 8];
            acc[0] = fmaf(bf_lo(va.x), wa, acc[0]); acc[1] = fmaf(bf_hi(va.x), wa, acc[1]);
            acc[2] = fmaf(bf_lo(va.y), wa, acc[2]); acc[3] = fmaf(bf_hi(va.y), wa, acc[3]);
            acc[4] = fmaf(bf_lo(va.z), wa, acc[4]); acc[5] = fmaf(bf_hi(va.z), wa, acc[5]);
            acc[6] = fmaf(bf_lo(va.w), wa, acc[6]); acc[7] = fmaf(bf_hi(va.w), wa, acc[7]);
            acc[0] = fmaf(bf_lo(vb.x), wb, acc[0]); acc[1] = fmaf(bf_hi(vb.x), wb, acc[1]);
            acc[2] = fmaf(bf_lo(vb.y), wb, acc[2]); acc[3] = fmaf(bf_hi(vb.y), wb, acc[3]);
            acc[4] = fmaf(bf_lo(vb.z), wb, acc[4]); acc[5] = fmaf(bf_hi(vb.z), wb, acc[5]);
            acc[6] = fmaf(bf_lo(vb.w), wb, acc[6]); acc[7] = fmaf(bf_hi(vb.w), wb, acc[7]);
            acc[0] = fmaf(bf_lo(vc.x), wc, acc[0]); acc[1] = fmaf(bf_hi(vc.x), wc, acc[1]);
            acc[2] = fmaf(bf_lo(vc.y), wc, acc[2]); acc[3] = fmaf(bf_hi(vc.y), wc, acc[3]);
            acc[4] = fmaf(bf_lo(vc.z), wc, acc[4]); acc[5] = fmaf(bf_hi(vc.z), wc, acc[5]);
            acc[6] = fmaf(bf_lo(vc.w), wc, acc[6]); acc[7] = fmaf(bf_hi(vc.w), wc, acc[7]);
            acc[0] = fmaf(bf_lo(vd.x), wd, acc[0]); acc[1] = fmaf(bf_hi(vd.x), wd, acc[1]);
            acc[2] = fmaf(bf_lo(vd.y), wd, acc[2]); acc[3] = fmaf(bf_hi(vd.y), wd, acc[3]);
            acc[4] = fmaf(bf_lo(vd.z), wd, acc[4]); acc[5] = fmaf(bf_hi(vd.z), wd, acc[5]);
            acc[6] = fmaf(bf_lo(vd.w), wd, acc[6]); acc[7] = fmaf(bf_hi(vd.w), wd, acc[7]);
        }
    }
    #pragma unroll
    for (int ofs = 32; ofs >= 1; ofs >>= 1) {
        ws0 += __shfl_xor(ws0, ofs, 64);
        ws1 += __shfl_xor(ws1, ofs, 64);
    }
    #pragma unroll
    for (int ofs = 8; ofs <= 32; ofs <<= 1) {
        #pragma unroll
        for (int i = 0; i < 8; ++i) acc[i] += __shfl_xor(acc[i], ofs, 64);
    }
    {
        const float inv = 1.f / ((li < 4) ? ws0 : ws1);
        float h0 = elu_f(acc[0] * inv + b1a.x);
        float h1 = elu_f(acc[1] * inv + b1a.y);
        float h2 = elu_f(acc[2] * inv + b1a.z);
        float h3 = elu_f(acc[3] * inv + b1a.w);
        float h4 = elu_f(acc[4] * inv + b1b.x);
        float h5 = elu_f(acc[5] * inv + b1b.y);
        float h6 = elu_f(acc[6] * inv + b1b.z);
        float h7 = elu_f(acc[7] * inv + b1b.w);
        if (sub == 0) {
            float4 p0; p0.x = h0; p0.y = h1; p0.z = h2; p0.w = h3;
            float4 p1; p1.x = h4; p1.y = h5; p1.z = h6; p1.w = h7;
            *(float4*)&hbuf[wave][li * 8]     = p0;
            *(float4*)&hbuf[wave][li * 8 + 4] = p1;
        }
    }
    __syncthreads();   // hbuf ready

    // Phase B: lane computes output cols (2*lane, 2*lane+1)
    float o0 = 0.f, o1 = 0.f;
    #pragma unroll
    for (int k = 0; k < C1; k += 2) {
        float2 hk = *(const float2*)&hbuf[wave][k];
        unsigned p0 = W2p[k * 64 + lane];
        unsigned p1 = W2p[(k + 1) * 64 + lane];
        o0 = fmaf(bf_lo(p0), hk.x, o0); o1 = fmaf(bf_hi(p0), hk.x, o1);
        o0 = fmaf(bf_lo(p1), hk.y, o0); o1 = fmaf(bf_hi(p1), hk.y, o1);
    }
    float ps = o0 * as2c.x + o1 * as2c.y;
    float pd = o0 * ad2c.x + o1 * ad2c.y;
    #pragma unroll
    for (int ofs = 32; ofs >= 1; ofs >>= 1) {
        ps += __shfl_xor(ps, ofs, 64);
        pd += __shfl_xor(pd, ofs, 64);
    }
    if (lane == 0) { a_s2[dst] = ps; a_d2[dst] = pd; }
    unsigned pk = (unsigned)f2bf(o0) | ((unsigned)f2bf(o1) << 16);
    xl2p[(size_t)dst * 64 + lane] = pk;
}

// ------- fused layer-2 attention + mean-pool: one wave per dst ---------------
__global__ __launch_bounds__(256) void k_attn2p(
    const int* __restrict__ beg_a, const int* __restrict__ end_a,
    const unsigned* __restrict__ csr,
    const float* __restrict__ a_s, const float* __restrict__ a_d,
    const unsigned short* __restrict__ xl,
    const float* __restrict__ b2, const int* __restrict__ batch,
    float* __restrict__ sums, float* __restrict__ cnts)
{
    const int wave = threadIdx.x >> 6, lane = threadIdx.x & 63;
    const int dst = blockIdx.x * 4 + wave;
    const int beg = beg_a[dst], end = end_a[dst];
    const float ad0 = a_d[dst];

    const int li = lane & 15, sub = lane >> 4;   // ch group li*8..+7; edge slot
    float acc[8];
    #pragma unroll
    for (int i = 0; i < 8; ++i) acc[i] = 0.f;
    float ws0 = 0.f;
    for (int base = beg; base < end; base += 64) {
        const int cnt = min(64, end - base);
        int s = 0; float w0 = 0.f;
        if (base + lane < end) {
            s = (int)csr[base + lane];
            float e0 = a_s[s] + ad0; e0 = e0 > 0.f ? e0 : NEG_SLOPE * e0;
            w0 = __expf(e0);
        }
        ws0 += w0;
        for (int k = 0; k < cnt; k += 16) {      // 4 batches of 4 edges
            const int ia = k + sub, ib = k + 4 + sub, ic = k + 8 + sub, id = k + 12 + sub;
            int   sa = __shfl(s, ia, 64);        // idx>=cnt -> w=0,s=0: harmless
            float wa = __shfl(w0, ia, 64);
            int   sb = __shfl(s, ib, 64);
            float wb = __shfl(w0, ib, 64);
            int   sc = __shfl(s, ic, 64);
            float wc = __shfl(w0, ic, 64);
            int   sd = __shfl(s, id, 64);
            float wd = __shfl(w0, id, 64);
            uint4 va = *(const uint4*)&xl[(size_t)sa * 128 + li * 8];
            uint4 vb = *(const uint4*)&xl[(size_t)sb * 128 + li * 8];
            uint4 vc = *(const uint4*)&xl[(size_t)sc * 128 + li * 8];
            uint4 vd = *(const uint4*)&xl[(size_t)sd * 128 + li * 8];
            acc[0] = fmaf(bf_lo(va.x), wa, acc[0]); acc[1] = fmaf(bf_hi(va.x), wa, acc[1]);
            acc[2] = fmaf(bf_lo(va.y), wa, acc[2]); acc[3] = fmaf(bf_hi(va.y), wa, acc[3]);
            acc[4] = fmaf(bf_lo(va.z), wa, acc[4]); acc[5] = fmaf(bf_hi(va.z), wa, acc[5]);
            acc[6] = fmaf(bf_lo(va.w), wa, acc[6]); acc[7] = fmaf(bf_hi(va.w), wa, acc[7]);
            acc[0] = fmaf(bf_lo(vb.x), wb, acc[0]); acc[1] = fmaf(bf_hi(vb.x), wb, acc[1]);
            acc[2] = fmaf(bf_lo(vb.y), wb, acc[2]); acc[3] = fmaf(bf_hi(vb.y), wb, acc[3]);
            acc[4] = fmaf(bf_lo(vb.z), wb, acc[4]); acc[5] = fmaf(bf_hi(vb.z), wb, acc[5]);
            acc[6] = fmaf(bf_lo(vb.w), wb, acc[6]); acc[7] = fmaf(bf_hi(vb.w), wb, acc[7]);
            acc[0] = fmaf(bf_lo(vc.x), wc, acc[0]); acc[1] = fmaf(bf_hi(vc.x), wc, acc[1]);
            acc[2] = fmaf(bf_lo(vc.y), wc, acc[2]); acc[3] = fmaf(bf_hi(vc.y), wc, acc[3]);
            acc[4] = fmaf(bf_lo(vc.z), wc, acc[4]); acc[5] = fmaf(bf_hi(vc.z), wc, acc[5]);
            acc[6] = fmaf(bf_lo(vc.w), wc, acc[6]); acc[7] = fmaf(bf_hi(vc.w), wc, acc[7]);
            acc[0] = fmaf(bf_lo(vd.x), wd, acc[0]); acc[1] = fmaf(bf_hi(vd.x), wd, acc[1]);
            acc[2] = fmaf(bf_lo(vd.y), wd, acc[2]); acc[3] = fmaf(bf_hi(vd.y), wd, acc[3]);
            acc[4] = fmaf(bf_lo(vd.z), wd, acc[4]); acc[5] = fmaf(bf_hi(vd.z), wd, acc[5]);
            acc[6] = fmaf(bf_lo(vd.w), wd, acc[6]); acc[7] = fmaf(bf_hi(vd.w), wd, acc[7]);
        }
    }
    #pragma unroll
    for (int ofs = 32; ofs >= 1; ofs >>= 1)
        ws0 += __shfl_xor(ws0, ofs, 64);
    #pragma unroll
    for (int ofs = 16; ofs <= 32; ofs <<= 1) {
        #pragma unroll
        for (int i = 0; i < 8; ++i) acc[i] += __shfl_xor(acc[i], ofs, 64);
    }
    if (lane < 16) {
        const float inv = 1.f / ws0;
        const int g = batch[dst];
        const float4 b2a = *(const float4*)&b2[li * 8];
        const float4 b2b = *(const float4*)&b2[li * 8 + 4];
        float* sg = &sums[(size_t)g * OUT_CH + li * 8];
        atomicAdd(&sg[0], elu_f(acc[0] * inv + b2a.x));
        atomicAdd(&sg[1], elu_f(acc[1] * inv + b2a.y));
        atomicAdd(&sg[2], elu_f(acc[2] * inv + b2a.z));
        atomicAdd(&sg[3], elu_f(acc[3] * inv + b2a.w));
        atomicAdd(&sg[4], elu_f(acc[4] * inv + b2b.x));
        atomicAdd(&sg[5], elu_f(acc[5] * inv + b2b.y));
        atomicAdd(&sg[6], elu_f(acc[6] * inv + b2b.z));
        atomicAdd(&sg[7], elu_f(acc[7] * inv + b2b.w));
        if (lane == 0) atomicAdd(&cnts[g], 1.f);
    }
}

__global__ __launch_bounds__(256) void k_final(
    const float* __restrict__ sums, const float* __restrict__ cnts,
    float* __restrict__ out)
{
    int i = blockIdx.x * 256 + threadIdx.x;
    if (i >= N_GRAPHS * OUT_CH) return;
    out[i] = sums[i] / fmaxf(cnts[i >> 7], 1.f);
}

extern "C" void kernel_launch(void* const* d_in, const int* in_sizes, int n_in,
                              void* d_out, int out_size, void* d_ws, size_t ws_size,
                              hipStream_t stream)
{
    const float* x    = (const float*)d_in[0];
    const int*   ei   = (const int*)d_in[1];
    const int*   batch= (const int*)d_in[2];
    const float* W1   = (const float*)d_in[3];
    const float* as1  = (const float*)d_in[4];
    const float* ad1  = (const float*)d_in[5];
    const float* b1   = (const float*)d_in[6];
    const float* W2   = (const float*)d_in[7];
    const float* as2  = (const float*)d_in[8];
    const float* ad2  = (const float*)d_in[9];
    const float* b2   = (const float*)d_in[10];

    float* ws = (float*)d_ws;
    size_t o = 0;
    unsigned short* xl1b = (unsigned short*)(ws + o); o += (size_t)N_NODES * C1 / 2;
    unsigned*       xl2p = (unsigned*)(ws + o);       o += (size_t)N_NODES * 64;
    float*    a_s1 = ws + o; o += (size_t)N_NODES * 2;
    float*    a_d1 = ws + o; o += (size_t)N_NODES * 2;
    float*    a_s2 = ws + o; o += (size_t)N_NODES;
    float*    a_d2 = ws + o; o += (size_t)N_NODES;
    unsigned* bbuf = (unsigned*)(ws + o); o += (size_t)NBUCK * BCAP;
    int*      beg  = (int*)(ws + o); o += (size_t)N_NODES;
    int*      end  = (int*)(ws + o); o += (size_t)N_NODES;
    size_t zero_start = o;
    int*      gcur = (int*)(ws + o); o += (size_t)NBUCK;
    float*    sums = ws + o;         o += (size_t)N_GRAPHS * OUT_CH;
    float*    cnts = ws + o;         o += (size_t)N_GRAPHS;
    size_t zero_bytes = (o - zero_start) * sizeof(float);
    hipMemsetAsync(ws + zero_start, 0, zero_bytes, stream);

    const int nchunks = (E_TOT + CHUNK - 1) / CHUNK;   // 202
    k_bin<<<nchunks, 256, 0, stream>>>(ei, gcur, bbuf);
    k_bsort<<<NBUCK, 256, 0, stream>>>(gcur, bbuf, beg, end);

    k_gemm1<<<2048, 256, 0, stream>>>(x, W1, as1, ad1, xl1b, a_s1, a_d1);
    k_attn1g2<<<N_NODES / 4, 256, 0, stream>>>(beg, end, bbuf, a_s1, a_d1, xl1b,
                                               b1, W2, as2, ad2, xl2p, a_s2, a_d2);
    k_attn2p<<<N_NODES / 4, 256, 0, stream>>>(beg, end, bbuf, a_s2, a_d2,
                                              (const unsigned short*)xl2p,
                                              b2, batch, sums, cnts);
    k_final<<<(N_GRAPHS * OUT_CH + 255) / 256, 256, 0, stream>>>(sums, cnts, (float*)d_out);
}

// Round 11
// 324.516 us; speedup vs baseline: 3.1020x; 3.1020x over previous
//
#include <hip/hip_runtime.h>

#define N_NODES 50000
#define N_EDGES 1600000
#define E_TOT   (N_EDGES + N_NODES)   // 1,650,000 incl. self-loops
#define IN_CH   128
#define C1      64                    // heads(2) * hid(32)
#define OUT_CH  128
#define N_GRAPHS 64
#define NEG_SLOPE 0.2f

#define BSH   7                        // 128 dsts per bucket
#define NBUCK ((N_NODES + 127) / 128)  // 391
#define BCAP  5120                     // per-bucket region cap (mean 4220, ~14 sigma)
#define CHUNK 8192                     // edges per k_bin workgroup
#define PN    32                       // nodes per k_pool block

__device__ __forceinline__ float elu_f(float v) {
    return v > 0.f ? v : (__expf(v) - 1.f);
}
__device__ __forceinline__ unsigned short f2bf(float f) {   // RNE
    unsigned u = __float_as_uint(f);
    return (unsigned short)((u + 0x7FFFu + ((u >> 16) & 1u)) >> 16);
}
__device__ __forceinline__ float bf_lo(unsigned u) { return __uint_as_float(u << 16); }
__device__ __forceinline__ float bf_hi(unsigned u) { return __uint_as_float(u & 0xFFFF0000u); }

// ---------------- GEMM1: xl1(bf16) = x @ W1, fused per-head attention dots ---
__global__ __launch_bounds__(256) void k_gemm1(
    const float* __restrict__ x, const float* __restrict__ W1,
    const float* __restrict__ att_s, const float* __restrict__ att_d,
    unsigned short* __restrict__ xl1, float* __restrict__ a_s, float* __restrict__ a_d)
{
    __shared__ float Ws[IN_CH * C1];   // 32 KB
    __shared__ float xr[4][IN_CH];
    const int t = threadIdx.x, wave = t >> 6, lane = t & 63;
    for (int i = t; i < IN_CH * C1; i += 256) Ws[i] = W1[i];
    __syncthreads();
    const float as_c = att_s[lane], ad_c = att_d[lane];
    const int ngroups = N_NODES / 4;   // 12500, exact
    for (int g = blockIdx.x; g < ngroups; g += gridDim.x) {
        const int r = g * 4 + wave;
        xr[wave][lane]      = x[r * IN_CH + lane];
        xr[wave][lane + 64] = x[r * IN_CH + lane + 64];
        __syncthreads();
        float acc = 0.f;
        #pragma unroll
        for (int k4 = 0; k4 < IN_CH / 4; ++k4) {
            float4 xv = *(const float4*)&xr[wave][k4 * 4];
            acc = fmaf(xv.x, Ws[(k4*4+0)*C1 + lane], acc);
            acc = fmaf(xv.y, Ws[(k4*4+1)*C1 + lane], acc);
            acc = fmaf(xv.z, Ws[(k4*4+2)*C1 + lane], acc);
            acc = fmaf(xv.w, Ws[(k4*4+3)*C1 + lane], acc);
        }
        xl1[r * C1 + lane] = f2bf(acc);
        float ps = acc * as_c, pd = acc * ad_c;
        #pragma unroll
        for (int m = 16; m >= 1; m >>= 1) {
            ps += __shfl_xor(ps, m, 32);
            pd += __shfl_xor(pd, m, 32);
        }
        if ((lane & 31) == 0) {
            a_s[r * 2 + (lane >> 5)] = ps;
            a_d[r * 2 + (lane >> 5)] = pd;
        }
        __syncthreads();
    }
}

// ---------------- pass 1: LDS-staged binning by dst>>7 ----------------------
__global__ __launch_bounds__(256) void k_bin(
    const int* __restrict__ ei, int* __restrict__ gcur, unsigned* __restrict__ bbuf)
{
    __shared__ int cnt[512];               // counts -> inclusive scan (512 >= NBUCK)
    __shared__ int base[NBUCK];
    __shared__ int cnt2[NBUCK];
    __shared__ int gpos[NBUCK];
    __shared__ unsigned stage[CHUNK];      // 32 KB
    __shared__ unsigned short bof[CHUNK];  // 16 KB
    const int t = threadIdx.x;
    const long long e0 = (long long)blockIdx.x * CHUNK;
    const int nE = (int)min((long long)CHUNK, (long long)E_TOT - e0);

    cnt[t] = 0; cnt[t + 256] = 0;
    for (int b = t; b < NBUCK; b += 256) cnt2[b] = 0;
    __syncthreads();

    const int per = CHUNK / 256;           // 32
    int myb[per]; unsigned mye[per];
    #pragma unroll
    for (int i = 0; i < per; ++i) {
        int idx = t + 256 * i;
        myb[i] = -1;
        if (idx < nE) {
            long long e = e0 + idx;
            int s, d;
            if (e < N_EDGES) { s = ei[e]; d = ei[N_EDGES + e]; }
            else             { s = d = (int)(e - N_EDGES); }
            myb[i] = d >> BSH;
            mye[i] = ((unsigned)(d & 127) << 17) | (unsigned)s;
            atomicAdd(&cnt[myb[i]], 1);
        }
    }
    __syncthreads();
    for (int ofs = 1; ofs < 512; ofs <<= 1) {
        int v0 = (t >= ofs) ? cnt[t - ofs] : 0;
        int v1 = cnt[t + 256 - ofs];
        __syncthreads();
        cnt[t] += v0; cnt[t + 256] += v1;
        __syncthreads();
    }
    for (int b = t; b < NBUCK; b += 256) {
        base[b] = (b == 0) ? 0 : cnt[b - 1];
        int c = cnt[b] - base[b];
        gpos[b] = (c > 0) ? atomicAdd(&gcur[b], c) : 0;
    }
    __syncthreads();
    #pragma unroll
    for (int i = 0; i < per; ++i) {
        if (myb[i] >= 0) {
            int slot = base[myb[i]] + atomicAdd(&cnt2[myb[i]], 1);
            stage[slot] = mye[i];
            bof[slot] = (unsigned short)myb[i];
        }
    }
    __syncthreads();
    for (int i = t; i < nE; i += 256) {
        int b = bof[i];
        int pos = gpos[b] + (i - base[b]);
        if (pos < BCAP)
            bbuf[(size_t)b * BCAP + pos] = stage[i];
    }
}

// ---------------- pass 2: per-bucket counting sort, emits beg/end -----------
__global__ __launch_bounds__(256) void k_bsort(
    const int* __restrict__ gcur, unsigned* __restrict__ bbuf,
    int* __restrict__ beg, int* __restrict__ end)
{
    __shared__ unsigned est[BCAP];   // 20 KB
    __shared__ unsigned sst[BCAP];   // 20 KB
    __shared__ int c[128], lbase[128], c2[128];
    const int b = blockIdx.x, t = threadIdx.x;
    const int n = min(gcur[b], BCAP);
    unsigned* reg = bbuf + (size_t)b * BCAP;
    for (int i = t; i < n; i += 256) est[i] = reg[i];
    if (t < 128) { c[t] = 0; c2[t] = 0; }
    __syncthreads();
    for (int i = t; i < n; i += 256) atomicAdd(&c[est[i] >> 17], 1);
    __syncthreads();
    for (int ofs = 1; ofs < 128; ofs <<= 1) {
        int v = (t < 128 && t >= ofs) ? c[t - ofs] : 0;
        __syncthreads();
        if (t < 128) c[t] += v;
        __syncthreads();
    }
    if (t < 128) {
        lbase[t] = (t == 0) ? 0 : c[t - 1];
        int dst = (b << BSH) + t;
        if (dst < N_NODES) {
            beg[dst] = b * BCAP + lbase[t];
            end[dst] = b * BCAP + c[t];
        }
    }
    __syncthreads();
    for (int i = t; i < n; i += 256) {
        unsigned v = est[i];
        int dl = (int)(v >> 17);
        int pos = lbase[dl] + atomicAdd(&c2[dl], 1);
        sst[pos] = v & 0x1FFFFu;
    }
    __syncthreads();
    for (int i = t; i < n; i += 256) reg[i] = sst[i];
}

// ------- fused layer-1 attention + GEMM2: one wave per dst -------------------
// Phase A: GAT softmax-aggregate (CH=64, H=2), 8 lanes/edge, 4x8 edges/iter.
// Phase B: h = elu(row + b1); xl2 = h @ W2 (bf16 W2 in LDS); fused a_s2/a_d2.
// NOTE: all __shfl executed wave-uniformly (ds_bpermute reads 0 from
// exec-inactive source lanes — divergent shuffles corrupt the weights).
__global__ __launch_bounds__(256) void k_attn1g2(
    const int* __restrict__ beg_a, const int* __restrict__ end_a,
    const unsigned* __restrict__ csr,
    const float* __restrict__ a_s, const float* __restrict__ a_d,
    const unsigned short* __restrict__ xl,
    const float* __restrict__ b1, const float* __restrict__ W2,
    const float* __restrict__ att_s2, const float* __restrict__ att_d2,
    unsigned* __restrict__ xl2p,          // bf16x2-packed xl2, [N][64] words
    float* __restrict__ a_s2, float* __restrict__ a_d2)
{
    __shared__ unsigned W2p[C1 * 64];     // 16 KB: row k, col-pair p -> (2p,2p+1)
    __shared__ float hbuf[4][C1];         // 1 KB per-wave h rows
    const int t = threadIdx.x, wave = t >> 6, lane = t & 63;
    for (int i = t; i < C1 * 64; i += 256) {
        int k = i >> 6, p = i & 63;
        unsigned lo = f2bf(W2[k * 128 + 2 * p]);
        unsigned hi = f2bf(W2[k * 128 + 2 * p + 1]);
        W2p[i] = lo | (hi << 16);
    }
    const int dst = blockIdx.x * 4 + wave;           // grid = 12500
    const int beg = beg_a[dst], end = end_a[dst];
    const float ad0 = a_d[dst * 2], ad1 = a_d[dst * 2 + 1];
    const int li = lane & 7, sub = lane >> 3;
    const float4 b1a = *(const float4*)&b1[li * 8];
    const float4 b1b = *(const float4*)&b1[li * 8 + 4];
    const float2 as2c = *(const float2*)&att_s2[2 * lane];
    const float2 ad2c = *(const float2*)&att_d2[2 * lane];
    __syncthreads();

    float acc[8];
    #pragma unroll
    for (int i = 0; i < 8; ++i) acc[i] = 0.f;
    float ws0 = 0.f, ws1 = 0.f;
    for (int base = beg; base < end; base += 64) {
        const int cnt = min(64, end - base);
        int s = 0; float w0 = 0.f, w1 = 0.f;
        if (base + lane < end) {
            s = (int)csr[base + lane];
            float e0 = a_s[s * 2] + ad0;     e0 = e0 > 0.f ? e0 : NEG_SLOPE * e0;
            float e1 = a_s[s * 2 + 1] + ad1; e1 = e1 > 0.f ? e1 : NEG_SLOPE * e1;
            w0 = __expf(e0);
            w1 = __expf(e1);
        }
        ws0 += w0; ws1 += w1;
        for (int k = 0; k < cnt; k += 32) {      // 4 batches of 8 edges
            const int ia = k + sub, ib = k + 8 + sub, ic = k + 16 + sub, id = k + 24 + sub;
            // uniform shuffles, per-lane select AFTER (exec-mask safety)
            int   sa  = __shfl(s, ia, 64);       // idx>=cnt -> w=0,s=0: harmless
            float wa0 = __shfl(w0, ia, 64);
            float wa1 = __shfl(w1, ia, 64);
            int   sb  = __shfl(s, ib, 64);
            float wb0 = __shfl(w0, ib, 64);
            float wb1 = __shfl(w1, ib, 64);
            int   sc  = __shfl(s, ic, 64);
            float wc0 = __shfl(w0, ic, 64);
            float wc1 = __shfl(w1, ic, 64);
            int   sd  = __shfl(s, id, 64);
            float wd0 = __shfl(w0, id, 64);
            float wd1 = __shfl(w1, id, 64);
            float wa = (li < 4) ? wa0 : wa1;
            float wb = (li < 4) ? wb0 : wb1;
            float wc = (li < 4) ? wc0 : wc1;
            float wd = (li < 4) ? wd0 : wd1;
            uint4 va = *(const uint4*)&xl[(size_t)sa * 64 + li * 8];
            uint4 vb = *(const uint4*)&xl[(size_t)sb * 64 + li * 8];
            uint4 vc = *(const uint4*)&xl[(size_t)sc * 64 + li * 8];
            uint4 vd = *(const uint4*)&xl[(size_t)sd * 64 + li * 8];
            acc[0] = fmaf(bf_lo(va.x), wa, acc[0]); acc[1] = fmaf(bf_hi(va.x), wa, acc[1]);
            acc[2] = fmaf(bf_lo(va.y), wa, acc[2]); acc[3] = fmaf(bf_hi(va.y), wa, acc[3]);
            acc[4] = fmaf(bf_lo(va.z), wa, acc[4]); acc[5] = fmaf(bf_hi(va.z), wa, acc[5]);
            acc[6] = fmaf(bf_lo(va.w), wa, acc[6]); acc[7] = fmaf(bf_hi(va.w), wa, acc[7]);
            acc[0] = fmaf(bf_lo(vb.x), wb, acc[0]); acc[1] = fmaf(bf_hi(vb.x), wb, acc[1]);
            acc[2] = fmaf(bf_lo(vb.y), wb, acc[2]); acc[3] = fmaf(bf_hi(vb.y), wb, acc[3]);
            acc[4] = fmaf(bf_lo(vb.z), wb, acc[4]); acc[5] = fmaf(bf_hi(vb.z), wb, acc[5]);
            acc[6] = fmaf(bf_lo(vb.w), wb, acc[6]); acc[7] = fmaf(bf_hi(vb.w), wb, acc[7]);
            acc[0] = fmaf(bf_lo(vc.x), wc, acc[0]); acc[1] = fmaf(bf_hi(vc.x), wc, acc[1]);
            acc[2] = fmaf(bf_lo(vc.y), wc, acc[2]); acc[3] = fmaf(bf_hi(vc.y), wc, acc[3]);
            acc[4] = fmaf(bf_lo(vc.z), wc, acc[4]); acc[5] = fmaf(bf_hi(vc.z), wc, acc[5]);
            acc[6] = fmaf(bf_lo(vc.w), wc, acc[6]); acc[7] = fmaf(bf_hi(vc.w), wc, acc[7]);
            acc[0] = fmaf(bf_lo(vd.x), wd, acc[0]); acc[1] = fmaf(bf_hi(vd.x), wd, acc[1]);
            acc[2] = fmaf(bf_lo(vd.y), wd, acc[2]); acc[3] = fmaf(bf_hi(vd.y), wd, acc[3]);
            acc[4] = fmaf(bf_lo(vd.z), wd, acc[4]); acc[5] = fmaf(bf_hi(vd.z), wd, acc[5]);
            acc[6] = fmaf(bf_lo(vd.w), wd, acc[6]); acc[7] = fmaf(bf_hi(vd.w), wd, acc[7]);
        }
    }
    #pragma unroll
    for (int ofs = 32; ofs >= 1; ofs >>= 1) {
        ws0 += __shfl_xor(ws0, ofs, 64);
        ws1 += __shfl_xor(ws1, ofs, 64);
    }
    #pragma unroll
    for (int ofs = 8; ofs <= 32; ofs <<= 1) {
        #pragma unroll
        for (int i = 0; i < 8; ++i) acc[i] += __shfl_xor(acc[i], ofs, 64);
    }
    {
        const float inv = 1.f / ((li < 4) ? ws0 : ws1);
        float h0 = elu_f(acc[0] * inv + b1a.x);
        float h1 = elu_f(acc[1] * inv + b1a.y);
        float h2 = elu_f(acc[2] * inv + b1a.z);
        float h3 = elu_f(acc[3] * inv + b1a.w);
        float h4 = elu_f(acc[4] * inv + b1b.x);
        float h5 = elu_f(acc[5] * inv + b1b.y);
        float h6 = elu_f(acc[6] * inv + b1b.z);
        float h7 = elu_f(acc[7] * inv + b1b.w);
        if (sub == 0) {
            float4 p0; p0.x = h0; p0.y = h1; p0.z = h2; p0.w = h3;
            float4 p1; p1.x = h4; p1.y = h5; p1.z = h6; p1.w = h7;
            *(float4*)&hbuf[wave][li * 8]     = p0;
            *(float4*)&hbuf[wave][li * 8 + 4] = p1;
        }
    }
    __syncthreads();   // hbuf ready

    // Phase B: lane computes output cols (2*lane, 2*lane+1)
    float o0 = 0.f, o1 = 0.f;
    #pragma unroll
    for (int k = 0; k < C1; k += 2) {
        float2 hk = *(const float2*)&hbuf[wave][k];
        unsigned p0 = W2p[k * 64 + lane];
        unsigned p1 = W2p[(k + 1) * 64 + lane];
        o0 = fmaf(bf_lo(p0), hk.x, o0); o1 = fmaf(bf_hi(p0), hk.x, o1);
        o0 = fmaf(bf_lo(p1), hk.y, o0); o1 = fmaf(bf_hi(p1), hk.y, o1);
    }
    float ps = o0 * as2c.x + o1 * as2c.y;
    float pd = o0 * ad2c.x + o1 * ad2c.y;
    #pragma unroll
    for (int ofs = 32; ofs >= 1; ofs >>= 1) {
        ps += __shfl_xor(ps, ofs, 64);
        pd += __shfl_xor(pd, ofs, 64);
    }
    if (lane == 0) { a_s2[dst] = ps; a_d2[dst] = pd; }
    unsigned pk = (unsigned)f2bf(o0) | ((unsigned)f2bf(o1) << 16);
    xl2p[(size_t)dst * 64 + lane] = pk;
}

// ------- layer-2 attention: coalesced out2 write (NO per-graph atomics) ------
__global__ __launch_bounds__(256) void k_attn2(
    const int* __restrict__ beg_a, const int* __restrict__ end_a,
    const unsigned* __restrict__ csr,
    const float* __restrict__ a_s, const float* __restrict__ a_d,
    const unsigned short* __restrict__ xl, float* __restrict__ out)
{
    const int wave = threadIdx.x >> 6, lane = threadIdx.x & 63;
    const int dst = blockIdx.x * 4 + wave;
    const int beg = beg_a[dst], end = end_a[dst];
    const float ad0 = a_d[dst];

    const int li = lane & 15, sub = lane >> 4;   // ch group li*8..+7; edge slot
    float acc[8];
    #pragma unroll
    for (int i = 0; i < 8; ++i) acc[i] = 0.f;
    float ws0 = 0.f;
    for (int base = beg; base < end; base += 64) {
        const int cnt = min(64, end - base);
        int s = 0; float w0 = 0.f;
        if (base + lane < end) {
            s = (int)csr[base + lane];
            float e0 = a_s[s] + ad0; e0 = e0 > 0.f ? e0 : NEG_SLOPE * e0;
            w0 = __expf(e0);
        }
        ws0 += w0;
        for (int k = 0; k < cnt; k += 16) {      // 4 batches of 4 edges
            const int ia = k + sub, ib = k + 4 + sub, ic = k + 8 + sub, id = k + 12 + sub;
            int   sa = __shfl(s, ia, 64);        // idx>=cnt -> w=0,s=0: harmless
            float wa = __shfl(w0, ia, 64);
            int   sb = __shfl(s, ib, 64);
            float wb = __shfl(w0, ib, 64);
            int   sc = __shfl(s, ic, 64);
            float wc = __shfl(w0, ic, 64);
            int   sd = __shfl(s, id, 64);
            float wd = __shfl(w0, id, 64);
            uint4 va = *(const uint4*)&xl[(size_t)sa * 128 + li * 8];
            uint4 vb = *(const uint4*)&xl[(size_t)sb * 128 + li * 8];
            uint4 vc = *(const uint4*)&xl[(size_t)sc * 128 + li * 8];
            uint4 vd = *(const uint4*)&xl[(size_t)sd * 128 + li * 8];
            acc[0] = fmaf(bf_lo(va.x), wa, acc[0]); acc[1] = fmaf(bf_hi(va.x), wa, acc[1]);
            acc[2] = fmaf(bf_lo(va.y), wa, acc[2]); acc[3] = fmaf(bf_hi(va.y), wa, acc[3]);
            acc[4] = fmaf(bf_lo(va.z), wa, acc[4]); acc[5] = fmaf(bf_hi(va.z), wa, acc[5]);
            acc[6] = fmaf(bf_lo(va.w), wa, acc[6]); acc[7] = fmaf(bf_hi(va.w), wa, acc[7]);
            acc[0] = fmaf(bf_lo(vb.x), wb, acc[0]); acc[1] = fmaf(bf_hi(vb.x), wb, acc[1]);
            acc[2] = fmaf(bf_lo(vb.y), wb, acc[2]); acc[3] = fmaf(bf_hi(vb.y), wb, acc[3]);
            acc[4] = fmaf(bf_lo(vb.z), wb, acc[4]); acc[5] = fmaf(bf_hi(vb.z), wb, acc[5]);
            acc[6] = fmaf(bf_lo(vb.w), wb, acc[6]); acc[7] = fmaf(bf_hi(vb.w), wb, acc[7]);
            acc[0] = fmaf(bf_lo(vc.x), wc, acc[0]); acc[1] = fmaf(bf_hi(vc.x), wc, acc[1]);
            acc[2] = fmaf(bf_lo(vc.y), wc, acc[2]); acc[3] = fmaf(bf_hi(vc.y), wc, acc[3]);
            acc[4] = fmaf(bf_lo(vc.z), wc, acc[4]); acc[5] = fmaf(bf_hi(vc.z), wc, acc[5]);
            acc[6] = fmaf(bf_lo(vc.w), wc, acc[6]); acc[7] = fmaf(bf_hi(vc.w), wc, acc[7]);
            acc[0] = fmaf(bf_lo(vd.x), wd, acc[0]); acc[1] = fmaf(bf_hi(vd.x), wd, acc[1]);
            acc[2] = fmaf(bf_lo(vd.y), wd, acc[2]); acc[3] = fmaf(bf_hi(vd.y), wd, acc[3]);
            acc[4] = fmaf(bf_lo(vd.z), wd, acc[4]); acc[5] = fmaf(bf_hi(vd.z), wd, acc[5]);
            acc[6] = fmaf(bf_lo(vd.w), wd, acc[6]); acc[7] = fmaf(bf_hi(vd.w), wd, acc[7]);
        }
    }
    #pragma unroll
    for (int ofs = 32; ofs >= 1; ofs >>= 1)
        ws0 += __shfl_xor(ws0, ofs, 64);
    #pragma unroll
    for (int ofs = 16; ofs <= 32; ofs <<= 1) {
        #pragma unroll
        for (int i = 0; i < 8; ++i) acc[i] += __shfl_xor(acc[i], ofs, 64);
    }
    if (lane < 16) {
        const float inv = 1.f / ws0;
        float4 r0, r1;
        r0.x = acc[0]*inv; r0.y = acc[1]*inv; r0.z = acc[2]*inv; r0.w = acc[3]*inv;
        r1.x = acc[4]*inv; r1.y = acc[5]*inv; r1.z = acc[6]*inv; r1.w = acc[7]*inv;
        *(float4*)&out[(size_t)dst * 128 + li * 8]     = r0;
        *(float4*)&out[(size_t)dst * 128 + li * 8 + 4] = r1;
    }
}

// ---------------- pooling: 32 nodes/block, 2 node-lanes x 128 ch -------------
// run-length pre-aggregation -> ~1-2 atomics per (block,channel): low contention
__global__ __launch_bounds__(256) void k_pool(
    const float* __restrict__ out2, const float* __restrict__ b2,
    const int* __restrict__ batch, float* __restrict__ sums, float* __restrict__ cnts)
{
    const int c    = threadIdx.x & 127;
    const int half = threadIdx.x >> 7;    // 0/1: even/odd nodes
    const int n0   = blockIdx.x * PN;
    const int nb   = n0 + half;
    if (nb >= N_NODES) return;
    const float bc = b2[c];
    float acc = 0.f;
    int cur = batch[nb], cnt = 0;
    for (int i = half; i < PN; i += 2) {
        int n = n0 + i;
        if (n >= N_NODES) break;
        int g = batch[n];
        if (g != cur) {
            atomicAdd(&sums[cur * OUT_CH + c], acc);
            if (c == 0) atomicAdd(&cnts[cur], (float)cnt);
            acc = 0.f; cnt = 0; cur = g;
        }
        acc += elu_f(out2[(size_t)n * OUT_CH + c] + bc);
        cnt++;
    }
    if (cnt > 0) {
        atomicAdd(&sums[cur * OUT_CH + c], acc);
        if (c == 0) atomicAdd(&cnts[cur], (float)cnt);
    }
}

__global__ __launch_bounds__(256) void k_final(
    const float* __restrict__ sums, const float* __restrict__ cnts,
    float* __restrict__ out)
{
    int i = blockIdx.x * 256 + threadIdx.x;
    if (i >= N_GRAPHS * OUT_CH) return;
    out[i] = sums[i] / fmaxf(cnts[i >> 7], 1.f);
}

extern "C" void kernel_launch(void* const* d_in, const int* in_sizes, int n_in,
                              void* d_out, int out_size, void* d_ws, size_t ws_size,
                              hipStream_t stream)
{
    const float* x    = (const float*)d_in[0];
    const int*   ei   = (const int*)d_in[1];
    const int*   batch= (const int*)d_in[2];
    const float* W1   = (const float*)d_in[3];
    const float* as1  = (const float*)d_in[4];
    const float* ad1  = (const float*)d_in[5];
    const float* b1   = (const float*)d_in[6];
    const float* W2   = (const float*)d_in[7];
    const float* as2  = (const float*)d_in[8];
    const float* ad2  = (const float*)d_in[9];
    const float* b2   = (const float*)d_in[10];

    float* ws = (float*)d_ws;
    size_t o = 0;
    unsigned short* xl1b = (unsigned short*)(ws + o); o += (size_t)N_NODES * C1 / 2;
    unsigned*       xl2p = (unsigned*)(ws + o);       o += (size_t)N_NODES * 64;
    float*    a_s1 = ws + o; o += (size_t)N_NODES * 2;
    float*    a_d1 = ws + o; o += (size_t)N_NODES * 2;
    float*    a_s2 = ws + o; o += (size_t)N_NODES;
    float*    a_d2 = ws + o; o += (size_t)N_NODES;
    float*    out2 = ws + o; o += (size_t)N_NODES * OUT_CH;
    unsigned* bbuf = (unsigned*)(ws + o); o += (size_t)NBUCK * BCAP;
    int*      beg  = (int*)(ws + o); o += (size_t)N_NODES;
    int*      end  = (int*)(ws + o); o += (size_t)N_NODES;
    size_t zero_start = o;
    int*      gcur = (int*)(ws + o); o += (size_t)NBUCK;
    float*    sums = ws + o;         o += (size_t)N_GRAPHS * OUT_CH;
    float*    cnts = ws + o;         o += (size_t)N_GRAPHS;
    size_t zero_bytes = (o - zero_start) * sizeof(float);
    hipMemsetAsync(ws + zero_start, 0, zero_bytes, stream);

    const int nchunks = (E_TOT + CHUNK - 1) / CHUNK;   // 202
    k_bin<<<nchunks, 256, 0, stream>>>(ei, gcur, bbuf);
    k_bsort<<<NBUCK, 256, 0, stream>>>(gcur, bbuf, beg, end);

    k_gemm1<<<2048, 256, 0, stream>>>(x, W1, as1, ad1, xl1b, a_s1, a_d1);
    k_attn1g2<<<N_NODES / 4, 256, 0, stream>>>(beg, end, bbuf, a_s1, a_d1, xl1b,
                                               b1, W2, as2, ad2, xl2p, a_s2, a_d2);
    k_attn2<<<N_NODES / 4, 256, 0, stream>>>(beg, end, bbuf, a_s2, a_d2,
                                             (const unsigned short*)xl2p, out2);
    k_pool<<<(N_NODES + PN - 1) / PN, 256, 0, stream>>>(out2, b2, batch, sums, cnts);
    k_final<<<(N_GRAPHS * OUT_CH + 255) / 256, 256, 0, stream>>>(sums, cnts, (float*)d_out);
}

// Round 12
// 318.749 us; speedup vs baseline: 3.1582x; 1.0181x over previous
//
#include <hip/hip_runtime.h>

#define N_NODES 50000
#define N_EDGES 1600000
#define E_TOT   (N_EDGES + N_NODES)   // 1,650,000 incl. self-loops
#define IN_CH   128
#define C1      64                    // heads(2) * hid(32)
#define OUT_CH  128
#define N_GRAPHS 64
#define NEG_SLOPE 0.2f

#define BSH   7                        // 128 dsts per bucket
#define NBUCK ((N_NODES + 127) / 128)  // 391
#define BCAP  5120                     // per-bucket region cap (mean 4220, ~14 sigma)
#define CHUNK 8192                     // edges per k_bin workgroup
#define PN    32                       // nodes per k_pool block

__device__ __forceinline__ float elu_f(float v) {
    return v > 0.f ? v : (__expf(v) - 1.f);
}
__device__ __forceinline__ unsigned short f2bf(float f) {   // RNE
    unsigned u = __float_as_uint(f);
    return (unsigned short)((u + 0x7FFFu + ((u >> 16) & 1u)) >> 16);
}
__device__ __forceinline__ float bf_lo(unsigned u) { return __uint_as_float(u << 16); }
__device__ __forceinline__ float bf_hi(unsigned u) { return __uint_as_float(u & 0xFFFF0000u); }

// ---------------- GEMM1: xl1(bf16) = x @ W1, fused per-head attention dots ---
__global__ __launch_bounds__(256) void k_gemm1(
    const float* __restrict__ x, const float* __restrict__ W1,
    const float* __restrict__ att_s, const float* __restrict__ att_d,
    unsigned short* __restrict__ xl1, float* __restrict__ a_s, float* __restrict__ a_d)
{
    __shared__ float Ws[IN_CH * C1];   // 32 KB
    __shared__ float xr[4][IN_CH];
    const int t = threadIdx.x, wave = t >> 6, lane = t & 63;
    for (int i = t; i < IN_CH * C1; i += 256) Ws[i] = W1[i];
    __syncthreads();
    const float as_c = att_s[lane], ad_c = att_d[lane];
    const int ngroups = N_NODES / 4;   // 12500, exact
    for (int g = blockIdx.x; g < ngroups; g += gridDim.x) {
        const int r = g * 4 + wave;
        xr[wave][lane]      = x[r * IN_CH + lane];
        xr[wave][lane + 64] = x[r * IN_CH + lane + 64];
        __syncthreads();
        float acc = 0.f;
        #pragma unroll
        for (int k4 = 0; k4 < IN_CH / 4; ++k4) {
            float4 xv = *(const float4*)&xr[wave][k4 * 4];
            acc = fmaf(xv.x, Ws[(k4*4+0)*C1 + lane], acc);
            acc = fmaf(xv.y, Ws[(k4*4+1)*C1 + lane], acc);
            acc = fmaf(xv.z, Ws[(k4*4+2)*C1 + lane], acc);
            acc = fmaf(xv.w, Ws[(k4*4+3)*C1 + lane], acc);
        }
        xl1[r * C1 + lane] = f2bf(acc);
        float ps = acc * as_c, pd = acc * ad_c;
        #pragma unroll
        for (int m = 16; m >= 1; m >>= 1) {
            ps += __shfl_xor(ps, m, 32);
            pd += __shfl_xor(pd, m, 32);
        }
        if ((lane & 31) == 0) {
            a_s[r * 2 + (lane >> 5)] = ps;
            a_d[r * 2 + (lane >> 5)] = pd;
        }
        __syncthreads();
    }
}

// ---------------- pass 1: LDS-staged binning by dst>>7 ----------------------
__global__ __launch_bounds__(256) void k_bin(
    const int* __restrict__ ei, int* __restrict__ gcur, unsigned* __restrict__ bbuf)
{
    __shared__ int cnt[512];               // counts -> inclusive scan (512 >= NBUCK)
    __shared__ int base[NBUCK];
    __shared__ int cnt2[NBUCK];
    __shared__ int gpos[NBUCK];
    __shared__ unsigned stage[CHUNK];      // 32 KB
    __shared__ unsigned short bof[CHUNK];  // 16 KB
    const int t = threadIdx.x;
    const long long e0 = (long long)blockIdx.x * CHUNK;
    const int nE = (int)min((long long)CHUNK, (long long)E_TOT - e0);

    cnt[t] = 0; cnt[t + 256] = 0;
    for (int b = t; b < NBUCK; b += 256) cnt2[b] = 0;
    __syncthreads();

    const int per = CHUNK / 256;           // 32
    int myb[per]; unsigned mye[per];
    #pragma unroll
    for (int i = 0; i < per; ++i) {
        int idx = t + 256 * i;
        myb[i] = -1;
        if (idx < nE) {
            long long e = e0 + idx;
            int s, d;
            if (e < N_EDGES) { s = ei[e]; d = ei[N_EDGES + e]; }
            else             { s = d = (int)(e - N_EDGES); }
            myb[i] = d >> BSH;
            mye[i] = ((unsigned)(d & 127) << 17) | (unsigned)s;
            atomicAdd(&cnt[myb[i]], 1);
        }
    }
    __syncthreads();
    for (int ofs = 1; ofs < 512; ofs <<= 1) {
        int v0 = (t >= ofs) ? cnt[t - ofs] : 0;
        int v1 = cnt[t + 256 - ofs];
        __syncthreads();
        cnt[t] += v0; cnt[t + 256] += v1;
        __syncthreads();
    }
    for (int b = t; b < NBUCK; b += 256) {
        base[b] = (b == 0) ? 0 : cnt[b - 1];
        int c = cnt[b] - base[b];
        gpos[b] = (c > 0) ? atomicAdd(&gcur[b], c) : 0;
    }
    __syncthreads();
    #pragma unroll
    for (int i = 0; i < per; ++i) {
        if (myb[i] >= 0) {
            int slot = base[myb[i]] + atomicAdd(&cnt2[myb[i]], 1);
            stage[slot] = mye[i];
            bof[slot] = (unsigned short)myb[i];
        }
    }
    __syncthreads();
    for (int i = t; i < nE; i += 256) {
        int b = bof[i];
        int pos = gpos[b] + (i - base[b]);
        if (pos < BCAP)
            bbuf[(size_t)b * BCAP + pos] = stage[i];
    }
}

// ---------------- pass 2: per-bucket counting sort, emits beg/end -----------
__global__ __launch_bounds__(256) void k_bsort(
    const int* __restrict__ gcur, unsigned* __restrict__ bbuf,
    int* __restrict__ beg, int* __restrict__ end)
{
    __shared__ unsigned est[BCAP];   // 20 KB
    __shared__ unsigned sst[BCAP];   // 20 KB
    __shared__ int c[128], lbase[128], c2[128];
    const int b = blockIdx.x, t = threadIdx.x;
    const int n = min(gcur[b], BCAP);
    unsigned* reg = bbuf + (size_t)b * BCAP;
    for (int i = t; i < n; i += 256) est[i] = reg[i];
    if (t < 128) { c[t] = 0; c2[t] = 0; }
    __syncthreads();
    for (int i = t; i < n; i += 256) atomicAdd(&c[est[i] >> 17], 1);
    __syncthreads();
    for (int ofs = 1; ofs < 128; ofs <<= 1) {
        int v = (t < 128 && t >= ofs) ? c[t - ofs] : 0;
        __syncthreads();
        if (t < 128) c[t] += v;
        __syncthreads();
    }
    if (t < 128) {
        lbase[t] = (t == 0) ? 0 : c[t - 1];
        int dst = (b << BSH) + t;
        if (dst < N_NODES) {
            beg[dst] = b * BCAP + lbase[t];
            end[dst] = b * BCAP + c[t];
        }
    }
    __syncthreads();
    for (int i = t; i < n; i += 256) {
        unsigned v = est[i];
        int dl = (int)(v >> 17);
        int pos = lbase[dl] + atomicAdd(&c2[dl], 1);
        sst[pos] = v & 0x1FFFFu;
    }
    __syncthreads();
    for (int i = t; i < n; i += 256) reg[i] = sst[i];
}

// ------- fused layer-1 attention + GEMM2: one wave per dst -------------------
// Phase A: GAT softmax-aggregate (CH=64, H=2), 8 lanes/edge, up-to-4x8 edges/iter
// with WAVE-UNIFORM tail guards (mean degree 33: roundup(deg,8) slots, not 64).
// Phase B: h = elu(row + b1); xl2 = h @ W2 (bf16 W2 in LDS); fused a_s2/a_d2.
__global__ __launch_bounds__(256) void k_attn1g2(
    const int* __restrict__ beg_a, const int* __restrict__ end_a,
    const unsigned* __restrict__ csr,
    const float* __restrict__ a_s, const float* __restrict__ a_d,
    const unsigned short* __restrict__ xl,
    const float* __restrict__ b1, const float* __restrict__ W2,
    const float* __restrict__ att_s2, const float* __restrict__ att_d2,
    unsigned* __restrict__ xl2p,          // bf16x2-packed xl2, [N][64] words
    float* __restrict__ a_s2, float* __restrict__ a_d2)
{
    __shared__ unsigned W2p[C1 * 64];     // 16 KB: row k, col-pair p -> (2p,2p+1)
    __shared__ float hbuf[4][C1];         // 1 KB per-wave h rows
    const int t = threadIdx.x, wave = t >> 6, lane = t & 63;
    for (int i = t; i < C1 * 64; i += 256) {
        int k = i >> 6, p = i & 63;
        unsigned lo = f2bf(W2[k * 128 + 2 * p]);
        unsigned hi = f2bf(W2[k * 128 + 2 * p + 1]);
        W2p[i] = lo | (hi << 16);
    }
    const int dst = blockIdx.x * 4 + wave;           // grid = 12500
    const int beg = beg_a[dst], end = end_a[dst];
    const float ad0 = a_d[dst * 2], ad1 = a_d[dst * 2 + 1];
    const int li = lane & 7, sub = lane >> 3;
    const float4 b1a = *(const float4*)&b1[li * 8];
    const float4 b1b = *(const float4*)&b1[li * 8 + 4];
    const float2 as2c = *(const float2*)&att_s2[2 * lane];
    const float2 ad2c = *(const float2*)&att_d2[2 * lane];
    __syncthreads();

    float acc[8];
    #pragma unroll
    for (int i = 0; i < 8; ++i) acc[i] = 0.f;
    float ws0 = 0.f, ws1 = 0.f;
    for (int base = beg; base < end; base += 64) {
        const int cnt = min(64, end - base);   // wave-uniform
        int s = 0; float w0 = 0.f, w1 = 0.f;
        if (base + lane < end) {
            s = (int)csr[base + lane];
            float e0 = a_s[s * 2] + ad0;     e0 = e0 > 0.f ? e0 : NEG_SLOPE * e0;
            float e1 = a_s[s * 2 + 1] + ad1; e1 = e1 > 0.f ? e1 : NEG_SLOPE * e1;
            w0 = __expf(e0);
            w1 = __expf(e1);
        }
        ws0 += w0; ws1 += w1;
        for (int k = 0; k < cnt; k += 32) {
            // batch a (edges k..k+7) — always has at least 1 real edge
            {
                const int ia = k + sub;
                int   sa  = __shfl(s, ia, 64);
                float wa0 = __shfl(w0, ia, 64);
                float wa1 = __shfl(w1, ia, 64);
                float wa = (li < 4) ? wa0 : wa1;
                uint4 va = *(const uint4*)&xl[(size_t)sa * 64 + li * 8];
                acc[0] = fmaf(bf_lo(va.x), wa, acc[0]); acc[1] = fmaf(bf_hi(va.x), wa, acc[1]);
                acc[2] = fmaf(bf_lo(va.y), wa, acc[2]); acc[3] = fmaf(bf_hi(va.y), wa, acc[3]);
                acc[4] = fmaf(bf_lo(va.z), wa, acc[4]); acc[5] = fmaf(bf_hi(va.z), wa, acc[5]);
                acc[6] = fmaf(bf_lo(va.w), wa, acc[6]); acc[7] = fmaf(bf_hi(va.w), wa, acc[7]);
            }
            if (k + 8 < cnt) {      // wave-uniform guard
                const int ib = k + 8 + sub;
                int   sb  = __shfl(s, ib, 64);
                float wb0 = __shfl(w0, ib, 64);
                float wb1 = __shfl(w1, ib, 64);
                float wb = (li < 4) ? wb0 : wb1;
                uint4 vb = *(const uint4*)&xl[(size_t)sb * 64 + li * 8];
                acc[0] = fmaf(bf_lo(vb.x), wb, acc[0]); acc[1] = fmaf(bf_hi(vb.x), wb, acc[1]);
                acc[2] = fmaf(bf_lo(vb.y), wb, acc[2]); acc[3] = fmaf(bf_hi(vb.y), wb, acc[3]);
                acc[4] = fmaf(bf_lo(vb.z), wb, acc[4]); acc[5] = fmaf(bf_hi(vb.z), wb, acc[5]);
                acc[6] = fmaf(bf_lo(vb.w), wb, acc[6]); acc[7] = fmaf(bf_hi(vb.w), wb, acc[7]);
            }
            if (k + 16 < cnt) {
                const int ic = k + 16 + sub;
                int   sc  = __shfl(s, ic, 64);
                float wc0 = __shfl(w0, ic, 64);
                float wc1 = __shfl(w1, ic, 64);
                float wc = (li < 4) ? wc0 : wc1;
                uint4 vc = *(const uint4*)&xl[(size_t)sc * 64 + li * 8];
                acc[0] = fmaf(bf_lo(vc.x), wc, acc[0]); acc[1] = fmaf(bf_hi(vc.x), wc, acc[1]);
                acc[2] = fmaf(bf_lo(vc.y), wc, acc[2]); acc[3] = fmaf(bf_hi(vc.y), wc, acc[3]);
                acc[4] = fmaf(bf_lo(vc.z), wc, acc[4]); acc[5] = fmaf(bf_hi(vc.z), wc, acc[5]);
                acc[6] = fmaf(bf_lo(vc.w), wc, acc[6]); acc[7] = fmaf(bf_hi(vc.w), wc, acc[7]);
            }
            if (k + 24 < cnt) {
                const int id = k + 24 + sub;
                int   sd  = __shfl(s, id, 64);
                float wd0 = __shfl(w0, id, 64);
                float wd1 = __shfl(w1, id, 64);
                float wd = (li < 4) ? wd0 : wd1;
                uint4 vd = *(const uint4*)&xl[(size_t)sd * 64 + li * 8];
                acc[0] = fmaf(bf_lo(vd.x), wd, acc[0]); acc[1] = fmaf(bf_hi(vd.x), wd, acc[1]);
                acc[2] = fmaf(bf_lo(vd.y), wd, acc[2]); acc[3] = fmaf(bf_hi(vd.y), wd, acc[3]);
                acc[4] = fmaf(bf_lo(vd.z), wd, acc[4]); acc[5] = fmaf(bf_hi(vd.z), wd, acc[5]);
                acc[6] = fmaf(bf_lo(vd.w), wd, acc[6]); acc[7] = fmaf(bf_hi(vd.w), wd, acc[7]);
            }
        }
    }
    #pragma unroll
    for (int ofs = 32; ofs >= 1; ofs >>= 1) {
        ws0 += __shfl_xor(ws0, ofs, 64);
        ws1 += __shfl_xor(ws1, ofs, 64);
    }
    #pragma unroll
    for (int ofs = 8; ofs <= 32; ofs <<= 1) {
        #pragma unroll
        for (int i = 0; i < 8; ++i) acc[i] += __shfl_xor(acc[i], ofs, 64);
    }
    {
        const float inv = 1.f / ((li < 4) ? ws0 : ws1);
        float h0 = elu_f(acc[0] * inv + b1a.x);
        float h1 = elu_f(acc[1] * inv + b1a.y);
        float h2 = elu_f(acc[2] * inv + b1a.z);
        float h3 = elu_f(acc[3] * inv + b1a.w);
        float h4 = elu_f(acc[4] * inv + b1b.x);
        float h5 = elu_f(acc[5] * inv + b1b.y);
        float h6 = elu_f(acc[6] * inv + b1b.z);
        float h7 = elu_f(acc[7] * inv + b1b.w);
        if (sub == 0) {
            float4 p0; p0.x = h0; p0.y = h1; p0.z = h2; p0.w = h3;
            float4 p1; p1.x = h4; p1.y = h5; p1.z = h6; p1.w = h7;
            *(float4*)&hbuf[wave][li * 8]     = p0;
            *(float4*)&hbuf[wave][li * 8 + 4] = p1;
        }
    }
    __syncthreads();   // hbuf ready

    // Phase B: lane computes output cols (2*lane, 2*lane+1)
    float o0 = 0.f, o1 = 0.f;
    #pragma unroll
    for (int k = 0; k < C1; k += 2) {
        float2 hk = *(const float2*)&hbuf[wave][k];
        unsigned p0 = W2p[k * 64 + lane];
        unsigned p1 = W2p[(k + 1) * 64 + lane];
        o0 = fmaf(bf_lo(p0), hk.x, o0); o1 = fmaf(bf_hi(p0), hk.x, o1);
        o0 = fmaf(bf_lo(p1), hk.y, o0); o1 = fmaf(bf_hi(p1), hk.y, o1);
    }
    float ps = o0 * as2c.x + o1 * as2c.y;
    float pd = o0 * ad2c.x + o1 * ad2c.y;
    #pragma unroll
    for (int ofs = 32; ofs >= 1; ofs >>= 1) {
        ps += __shfl_xor(ps, ofs, 64);
        pd += __shfl_xor(pd, ofs, 64);
    }
    if (lane == 0) { a_s2[dst] = ps; a_d2[dst] = pd; }
    unsigned pk = (unsigned)f2bf(o0) | ((unsigned)f2bf(o1) << 16);
    xl2p[(size_t)dst * 64 + lane] = pk;
}

// ------- layer-2 attention: 16 lanes/edge, up-to-4x4 edges/iter w/ guards ----
__global__ __launch_bounds__(256) void k_attn2(
    const int* __restrict__ beg_a, const int* __restrict__ end_a,
    const unsigned* __restrict__ csr,
    const float* __restrict__ a_s, const float* __restrict__ a_d,
    const unsigned short* __restrict__ xl, float* __restrict__ out)
{
    const int wave = threadIdx.x >> 6, lane = threadIdx.x & 63;
    const int dst = blockIdx.x * 4 + wave;
    const int beg = beg_a[dst], end = end_a[dst];
    const float ad0 = a_d[dst];

    const int li = lane & 15, sub = lane >> 4;   // ch group li*8..+7; edge slot
    float acc[8];
    #pragma unroll
    for (int i = 0; i < 8; ++i) acc[i] = 0.f;
    float ws0 = 0.f;
    for (int base = beg; base < end; base += 64) {
        const int cnt = min(64, end - base);   // wave-uniform
        int s = 0; float w0 = 0.f;
        if (base + lane < end) {
            s = (int)csr[base + lane];
            float e0 = a_s[s] + ad0; e0 = e0 > 0.f ? e0 : NEG_SLOPE * e0;
            w0 = __expf(e0);
        }
        ws0 += w0;
        for (int k = 0; k < cnt; k += 16) {
            {
                const int ia = k + sub;
                int   sa = __shfl(s, ia, 64);
                float wa = __shfl(w0, ia, 64);
                uint4 va = *(const uint4*)&xl[(size_t)sa * 128 + li * 8];
                acc[0] = fmaf(bf_lo(va.x), wa, acc[0]); acc[1] = fmaf(bf_hi(va.x), wa, acc[1]);
                acc[2] = fmaf(bf_lo(va.y), wa, acc[2]); acc[3] = fmaf(bf_hi(va.y), wa, acc[3]);
                acc[4] = fmaf(bf_lo(va.z), wa, acc[4]); acc[5] = fmaf(bf_hi(va.z), wa, acc[5]);
                acc[6] = fmaf(bf_lo(va.w), wa, acc[6]); acc[7] = fmaf(bf_hi(va.w), wa, acc[7]);
            }
            if (k + 4 < cnt) {      // wave-uniform guard
                const int ib = k + 4 + sub;
                int   sb = __shfl(s, ib, 64);
                float wb = __shfl(w0, ib, 64);
                uint4 vb = *(const uint4*)&xl[(size_t)sb * 128 + li * 8];
                acc[0] = fmaf(bf_lo(vb.x), wb, acc[0]); acc[1] = fmaf(bf_hi(vb.x), wb, acc[1]);
                acc[2] = fmaf(bf_lo(vb.y), wb, acc[2]); acc[3] = fmaf(bf_hi(vb.y), wb, acc[3]);
                acc[4] = fmaf(bf_lo(vb.z), wb, acc[4]); acc[5] = fmaf(bf_hi(vb.z), wb, acc[5]);
                acc[6] = fmaf(bf_lo(vb.w), wb, acc[6]); acc[7] = fmaf(bf_hi(vb.w), wb, acc[7]);
            }
            if (k + 8 < cnt) {
                const int ic = k + 8 + sub;
                int   sc = __shfl(s, ic, 64);
                float wc = __shfl(w0, ic, 64);
                uint4 vc = *(const uint4*)&xl[(size_t)sc * 128 + li * 8];
                acc[0] = fmaf(bf_lo(vc.x), wc, acc[0]); acc[1] = fmaf(bf_hi(vc.x), wc, acc[1]);
                acc[2] = fmaf(bf_lo(vc.y), wc, acc[2]); acc[3] = fmaf(bf_hi(vc.y), wc, acc[3]);
                acc[4] = fmaf(bf_lo(vc.z), wc, acc[4]); acc[5] = fmaf(bf_hi(vc.z), wc, acc[5]);
                acc[6] = fmaf(bf_lo(vc.w), wc, acc[6]); acc[7] = fmaf(bf_hi(vc.w), wc, acc[7]);
            }
            if (k + 12 < cnt) {
                const int id = k + 12 + sub;
                int   sd = __shfl(s, id, 64);
                float wd = __shfl(w0, id, 64);
                uint4 vd = *(const uint4*)&xl[(size_t)sd * 128 + li * 8];
                acc[0] = fmaf(bf_lo(vd.x), wd, acc[0]); acc[1] = fmaf(bf_hi(vd.x), wd, acc[1]);
                acc[2] = fmaf(bf_lo(vd.y), wd, acc[2]); acc[3] = fmaf(bf_hi(vd.y), wd, acc[3]);
                acc[4] = fmaf(bf_lo(vd.z), wd, acc[4]); acc[5] = fmaf(bf_hi(vd.z), wd, acc[5]);
                acc[6] = fmaf(bf_lo(vd.w), wd, acc[6]); acc[7] = fmaf(bf_hi(vd.w), wd, acc[7]);
            }
        }
    }
    #pragma unroll
    for (int ofs = 32; ofs >= 1; ofs >>= 1)
        ws0 += __shfl_xor(ws0, ofs, 64);
    #pragma unroll
    for (int ofs = 16; ofs <= 32; ofs <<= 1) {
        #pragma unroll
        for (int i = 0; i < 8; ++i) acc[i] += __shfl_xor(acc[i], ofs, 64);
    }
    if (lane < 16) {
        const float inv = 1.f / ws0;
        float4 r0, r1;
        r0.x = acc[0]*inv; r0.y = acc[1]*inv; r0.z = acc[2]*inv; r0.w = acc[3]*inv;
        r1.x = acc[4]*inv; r1.y = acc[5]*inv; r1.z = acc[6]*inv; r1.w = acc[7]*inv;
        *(float4*)&out[(size_t)dst * 128 + li * 8]     = r0;
        *(float4*)&out[(size_t)dst * 128 + li * 8 + 4] = r1;
    }
}

// ---------------- pooling: 32 nodes/block, 2 node-lanes x 128 ch -------------
__global__ __launch_bounds__(256) void k_pool(
    const float* __restrict__ out2, const float* __restrict__ b2,
    const int* __restrict__ batch, float* __restrict__ sums, float* __restrict__ cnts)
{
    const int c    = threadIdx.x & 127;
    const int half = threadIdx.x >> 7;    // 0/1: even/odd nodes
    const int n0   = blockIdx.x * PN;
    const int nb   = n0 + half;
    if (nb >= N_NODES) return;
    const float bc = b2[c];
    float acc = 0.f;
    int cur = batch[nb], cnt = 0;
    for (int i = half; i < PN; i += 2) {
        int n = n0 + i;
        if (n >= N_NODES) break;
        int g = batch[n];
        if (g != cur) {
            atomicAdd(&sums[cur * OUT_CH + c], acc);
            if (c == 0) atomicAdd(&cnts[cur], (float)cnt);
            acc = 0.f; cnt = 0; cur = g;
        }
        acc += elu_f(out2[(size_t)n * OUT_CH + c] + bc);
        cnt++;
    }
    if (cnt > 0) {
        atomicAdd(&sums[cur * OUT_CH + c], acc);
        if (c == 0) atomicAdd(&cnts[cur], (float)cnt);
    }
}

__global__ __launch_bounds__(256) void k_final(
    const float* __restrict__ sums, const float* __restrict__ cnts,
    float* __restrict__ out)
{
    int i = blockIdx.x * 256 + threadIdx.x;
    if (i >= N_GRAPHS * OUT_CH) return;
    out[i] = sums[i] / fmaxf(cnts[i >> 7], 1.f);
}

extern "C" void kernel_launch(void* const* d_in, const int* in_sizes, int n_in,
                              void* d_out, int out_size, void* d_ws, size_t ws_size,
                              hipStream_t stream)
{
    const float* x    = (const float*)d_in[0];
    const int*   ei   = (const int*)d_in[1];
    const int*   batch= (const int*)d_in[2];
    const float* W1   = (const float*)d_in[3];
    const float* as1  = (const float*)d_in[4];
    const float* ad1  = (const float*)d_in[5];
    const float* b1   = (const float*)d_in[6];
    const float* W2   = (const float*)d_in[7];
    const float* as2  = (const float*)d_in[8];
    const float* ad2  = (const float*)d_in[9];
    const float* b2   = (const float*)d_in[10];

    float* ws = (float*)d_ws;
    size_t o = 0;
    unsigned short* xl1b = (unsigned short*)(ws + o); o += (size_t)N_NODES * C1 / 2;
    unsigned*       xl2p = (unsigned*)(ws + o);       o += (size_t)N_NODES * 64;
    float*    a_s1 = ws + o; o += (size_t)N_NODES * 2;
    float*    a_d1 = ws + o; o += (size_t)N_NODES * 2;
    float*    a_s2 = ws + o; o += (size_t)N_NODES;
    float*    a_d2 = ws + o; o += (size_t)N_NODES;
    float*    out2 = ws + o; o += (size_t)N_NODES * OUT_CH;
    unsigned* bbuf = (unsigned*)(ws + o); o += (size_t)NBUCK * BCAP;
    int*      beg  = (int*)(ws + o); o += (size_t)N_NODES;
    int*      end  = (int*)(ws + o); o += (size_t)N_NODES;
    size_t zero_start = o;
    int*      gcur = (int*)(ws + o); o += (size_t)NBUCK;
    float*    sums = ws + o;         o += (size_t)N_GRAPHS * OUT_CH;
    float*    cnts = ws + o;         o += (size_t)N_GRAPHS;
    size_t zero_bytes = (o - zero_start) * sizeof(float);
    hipMemsetAsync(ws + zero_start, 0, zero_bytes, stream);

    const int nchunks = (E_TOT + CHUNK - 1) / CHUNK;   // 202
    k_bin<<<nchunks, 256, 0, stream>>>(ei, gcur, bbuf);
    k_bsort<<<NBUCK, 256, 0, stream>>>(gcur, bbuf, beg, end);

    k_gemm1<<<2048, 256, 0, stream>>>(x, W1, as1, ad1, xl1b, a_s1, a_d1);
    k_attn1g2<<<N_NODES / 4, 256, 0, stream>>>(beg, end, bbuf, a_s1, a_d1, xl1b,
                                               b1, W2, as2, ad2, xl2p, a_s2, a_d2);
    k_attn2<<<N_NODES / 4, 256, 0, stream>>>(beg, end, bbuf, a_s2, a_d2,
                                             (const unsigned short*)xl2p, out2);
    k_pool<<<(N_NODES + PN - 1) / PN, 256, 0, stream>>>(out2, b2, batch, sums, cnts);
    k_final<<<(N_GRAPHS * OUT_CH + 255) / 256, 256, 0, stream>>>(sums, cnts, (float*)d_out);
}

// Round 13
// 298.876 us; speedup vs baseline: 3.3681x; 1.0665x over previous
//
#include <hip/hip_runtime.h>

#define N_NODES 50000
#define N_EDGES 1600000
#define E_TOT   (N_EDGES + N_NODES)   // 1,650,000 incl. self-loops
#define IN_CH   128
#define C1      64                    // heads(2) * hid(32)
#define OUT_CH  128
#define N_GRAPHS 64
#define NEG_SLOPE 0.2f

#define BSH   7                        // 128 dsts per bucket
#define NBUCK ((N_NODES + 127) / 128)  // 391
#define BCAP  5120                     // per-bucket region cap (mean 4220, ~14 sigma)
#define CHUNK 8192                     // edges per k_bin workgroup
#define PN    32                       // nodes per k_pool block

typedef __attribute__((ext_vector_type(8))) short bf16x8;
typedef __attribute__((ext_vector_type(4))) float f32x4;

__device__ __forceinline__ float elu_f(float v) {
    return v > 0.f ? v : (__expf(v) - 1.f);
}
__device__ __forceinline__ unsigned short f2bf(float f) {   // RNE
    unsigned u = __float_as_uint(f);
    return (unsigned short)((u + 0x7FFFu + ((u >> 16) & 1u)) >> 16);
}
__device__ __forceinline__ float bf_lo(unsigned u) { return __uint_as_float(u << 16); }
__device__ __forceinline__ float bf_hi(unsigned u) { return __uint_as_float(u & 0xFFFF0000u); }

// ---------------- GEMM1 via MFMA: xl1(bf16) = x @ W1, fused attention dots ---
// One block per 16-row tile (3125 blocks). Wave w owns col-tile n0=16w.
// A-frag (verified m120): A[m][k], m=lane&15, k=(lane>>4)*8+j — read from global.
// B-frag: B[k][n], n=lane&15, k=(lane>>4)*8+j — from W1^T bf16 in LDS (held in regs).
// C/D (verified m89/m91): col=lane&15, row=(lane>>4)*4+reg.
__global__ __launch_bounds__(256) void k_gemm1(
    const float* __restrict__ x, const float* __restrict__ W1,
    const float* __restrict__ att_s, const float* __restrict__ att_d,
    unsigned short* __restrict__ xl1, float* __restrict__ a_s, float* __restrict__ a_d)
{
    __shared__ unsigned short W1T[64][136];  // W1^T bf16, +8 pad (17.4 KB)
    __shared__ float psA[4][16], psD[4][16];
    const int t = threadIdx.x, wave = t >> 6, lane = t & 63;
    const int quad = lane >> 4, lm = lane & 15;
    for (int i = t; i < 128 * 64; i += 256)
        W1T[i & 63][i >> 6] = f2bf(W1[i]);   // W1T[c][k] = W1[k][c]
    __syncthreads();

    const int n0 = wave * 16;
    const int c  = n0 + lm;                  // this lane's output column
    bf16x8 bfr[4];
    #pragma unroll
    for (int s = 0; s < 4; ++s)
        bfr[s] = *(const bf16x8*)&W1T[c][s * 32 + quad * 8];
    const float asc = att_s[c], adc = att_d[c];

    const int r0 = blockIdx.x * 16;
    f32x4 acc = {0.f, 0.f, 0.f, 0.f};
    #pragma unroll
    for (int s = 0; s < 4; ++s) {
        const float* xp = &x[(size_t)(r0 + lm) * 128 + s * 32 + quad * 8];
        float4 xa = *(const float4*)xp;
        float4 xb = *(const float4*)(xp + 4);
        bf16x8 afr;
        afr[0] = (short)f2bf(xa.x); afr[1] = (short)f2bf(xa.y);
        afr[2] = (short)f2bf(xa.z); afr[3] = (short)f2bf(xa.w);
        afr[4] = (short)f2bf(xb.x); afr[5] = (short)f2bf(xb.y);
        afr[6] = (short)f2bf(xb.z); afr[7] = (short)f2bf(xb.w);
        acc = __builtin_amdgcn_mfma_f32_16x16x32_bf16(afr, bfr[s], acc, 0, 0, 0);
    }
    // acc[r] = (x@W1)[r0 + quad*4 + r][c]
    float psv[4], pdv[4];
    #pragma unroll
    for (int r = 0; r < 4; ++r) {
        float v = acc[r];
        xl1[(size_t)(r0 + quad * 4 + r) * 64 + c] = f2bf(v);
        psv[r] = v * asc;
        pdv[r] = v * adc;
    }
    #pragma unroll
    for (int ofs = 1; ofs <= 8; ofs <<= 1) {
        #pragma unroll
        for (int r = 0; r < 4; ++r) {
            psv[r] += __shfl_xor(psv[r], ofs, 64);
            pdv[r] += __shfl_xor(pdv[r], ofs, 64);
        }
    }
    if (lm == 0) {
        #pragma unroll
        for (int r = 0; r < 4; ++r) {
            psA[wave][quad * 4 + r] = psv[r];
            psD[wave][quad * 4 + r] = pdv[r];
        }
    }
    __syncthreads();
    if (t < 32) {     // waves 0,1 -> head 0 (cols 0-31); waves 2,3 -> head 1
        const int row = t & 15, h = t >> 4;
        a_s[(size_t)(r0 + row) * 2 + h] = psA[2 * h][row] + psA[2 * h + 1][row];
        a_d[(size_t)(r0 + row) * 2 + h] = psD[2 * h][row] + psD[2 * h + 1][row];
    }
}

// ---------------- pass 1: LDS-staged binning by dst>>7 ----------------------
__global__ __launch_bounds__(256) void k_bin(
    const int* __restrict__ ei, int* __restrict__ gcur, unsigned* __restrict__ bbuf)
{
    __shared__ int cnt[512];               // counts -> inclusive scan (512 >= NBUCK)
    __shared__ int base[NBUCK];
    __shared__ int cnt2[NBUCK];
    __shared__ int gpos[NBUCK];
    __shared__ unsigned stage[CHUNK];      // 32 KB
    __shared__ unsigned short bof[CHUNK];  // 16 KB
    const int t = threadIdx.x;
    const long long e0 = (long long)blockIdx.x * CHUNK;
    const int nE = (int)min((long long)CHUNK, (long long)E_TOT - e0);

    cnt[t] = 0; cnt[t + 256] = 0;
    for (int b = t; b < NBUCK; b += 256) cnt2[b] = 0;
    __syncthreads();

    const int per = CHUNK / 256;           // 32
    int myb[per]; unsigned mye[per];
    #pragma unroll
    for (int i = 0; i < per; ++i) {
        int idx = t + 256 * i;
        myb[i] = -1;
        if (idx < nE) {
            long long e = e0 + idx;
            int s, d;
            if (e < N_EDGES) { s = ei[e]; d = ei[N_EDGES + e]; }
            else             { s = d = (int)(e - N_EDGES); }
            myb[i] = d >> BSH;
            mye[i] = ((unsigned)(d & 127) << 17) | (unsigned)s;
            atomicAdd(&cnt[myb[i]], 1);
        }
    }
    __syncthreads();
    for (int ofs = 1; ofs < 512; ofs <<= 1) {
        int v0 = (t >= ofs) ? cnt[t - ofs] : 0;
        int v1 = cnt[t + 256 - ofs];
        __syncthreads();
        cnt[t] += v0; cnt[t + 256] += v1;
        __syncthreads();
    }
    for (int b = t; b < NBUCK; b += 256) {
        base[b] = (b == 0) ? 0 : cnt[b - 1];
        int c = cnt[b] - base[b];
        gpos[b] = (c > 0) ? atomicAdd(&gcur[b], c) : 0;
    }
    __syncthreads();
    #pragma unroll
    for (int i = 0; i < per; ++i) {
        if (myb[i] >= 0) {
            int slot = base[myb[i]] + atomicAdd(&cnt2[myb[i]], 1);
            stage[slot] = mye[i];
            bof[slot] = (unsigned short)myb[i];
        }
    }
    __syncthreads();
    for (int i = t; i < nE; i += 256) {
        int b = bof[i];
        int pos = gpos[b] + (i - base[b]);
        if (pos < BCAP)
            bbuf[(size_t)b * BCAP + pos] = stage[i];
    }
}

// ---------------- pass 2: per-bucket counting sort, emits beg/end -----------
__global__ __launch_bounds__(256) void k_bsort(
    const int* __restrict__ gcur, unsigned* __restrict__ bbuf,
    int* __restrict__ beg, int* __restrict__ end)
{
    __shared__ unsigned est[BCAP];   // 20 KB
    __shared__ unsigned sst[BCAP];   // 20 KB
    __shared__ int c[128], lbase[128], c2[128];
    const int b = blockIdx.x, t = threadIdx.x;
    const int n = min(gcur[b], BCAP);
    unsigned* reg = bbuf + (size_t)b * BCAP;
    for (int i = t; i < n; i += 256) est[i] = reg[i];
    if (t < 128) { c[t] = 0; c2[t] = 0; }
    __syncthreads();
    for (int i = t; i < n; i += 256) atomicAdd(&c[est[i] >> 17], 1);
    __syncthreads();
    for (int ofs = 1; ofs < 128; ofs <<= 1) {
        int v = (t < 128 && t >= ofs) ? c[t - ofs] : 0;
        __syncthreads();
        if (t < 128) c[t] += v;
        __syncthreads();
    }
    if (t < 128) {
        lbase[t] = (t == 0) ? 0 : c[t - 1];
        int dst = (b << BSH) + t;
        if (dst < N_NODES) {
            beg[dst] = b * BCAP + lbase[t];
            end[dst] = b * BCAP + c[t];
        }
    }
    __syncthreads();
    for (int i = t; i < n; i += 256) {
        unsigned v = est[i];
        int dl = (int)(v >> 17);
        int pos = lbase[dl] + atomicAdd(&c2[dl], 1);
        sst[pos] = v & 0x1FFFFu;
    }
    __syncthreads();
    for (int i = t; i < n; i += 256) reg[i] = sst[i];
}

// ------- fused layer-1 attention + GEMM2: one wave per dst -------------------
__global__ __launch_bounds__(256) void k_attn1g2(
    const int* __restrict__ beg_a, const int* __restrict__ end_a,
    const unsigned* __restrict__ csr,
    const float* __restrict__ a_s, const float* __restrict__ a_d,
    const unsigned short* __restrict__ xl,
    const float* __restrict__ b1, const float* __restrict__ W2,
    const float* __restrict__ att_s2, const float* __restrict__ att_d2,
    unsigned* __restrict__ xl2p,          // bf16x2-packed xl2, [N][64] words
    float* __restrict__ a_s2, float* __restrict__ a_d2)
{
    __shared__ unsigned W2p[C1 * 64];     // 16 KB: row k, col-pair p -> (2p,2p+1)
    __shared__ float hbuf[4][C1];         // 1 KB per-wave h rows
    const int t = threadIdx.x, wave = t >> 6, lane = t & 63;
    for (int i = t; i < C1 * 64; i += 256) {
        int k = i >> 6, p = i & 63;
        unsigned lo = f2bf(W2[k * 128 + 2 * p]);
        unsigned hi = f2bf(W2[k * 128 + 2 * p + 1]);
        W2p[i] = lo | (hi << 16);
    }
    const int dst = blockIdx.x * 4 + wave;           // grid = 12500
    const int beg = beg_a[dst], end = end_a[dst];
    const float ad0 = a_d[dst * 2], ad1 = a_d[dst * 2 + 1];
    const int li = lane & 7, sub = lane >> 3;
    const float4 b1a = *(const float4*)&b1[li * 8];
    const float4 b1b = *(const float4*)&b1[li * 8 + 4];
    const float2 as2c = *(const float2*)&att_s2[2 * lane];
    const float2 ad2c = *(const float2*)&att_d2[2 * lane];
    __syncthreads();

    float acc[8];
    #pragma unroll
    for (int i = 0; i < 8; ++i) acc[i] = 0.f;
    float ws0 = 0.f, ws1 = 0.f;
    for (int base = beg; base < end; base += 64) {
        const int cnt = min(64, end - base);   // wave-uniform
        int s = 0; float w0 = 0.f, w1 = 0.f;
        if (base + lane < end) {
            s = (int)csr[base + lane];
            float e0 = a_s[s * 2] + ad0;     e0 = e0 > 0.f ? e0 : NEG_SLOPE * e0;
            float e1 = a_s[s * 2 + 1] + ad1; e1 = e1 > 0.f ? e1 : NEG_SLOPE * e1;
            w0 = __expf(e0);
            w1 = __expf(e1);
        }
        ws0 += w0; ws1 += w1;
        for (int k = 0; k < cnt; k += 32) {
            {
                const int ia = k + sub;
                int   sa  = __shfl(s, ia, 64);
                float wa0 = __shfl(w0, ia, 64);
                float wa1 = __shfl(w1, ia, 64);
                float wa = (li < 4) ? wa0 : wa1;
                uint4 va = *(const uint4*)&xl[(size_t)sa * 64 + li * 8];
                acc[0] = fmaf(bf_lo(va.x), wa, acc[0]); acc[1] = fmaf(bf_hi(va.x), wa, acc[1]);
                acc[2] = fmaf(bf_lo(va.y), wa, acc[2]); acc[3] = fmaf(bf_hi(va.y), wa, acc[3]);
                acc[4] = fmaf(bf_lo(va.z), wa, acc[4]); acc[5] = fmaf(bf_hi(va.z), wa, acc[5]);
                acc[6] = fmaf(bf_lo(va.w), wa, acc[6]); acc[7] = fmaf(bf_hi(va.w), wa, acc[7]);
            }
            if (k + 8 < cnt) {      // wave-uniform guard
                const int ib = k + 8 + sub;
                int   sb  = __shfl(s, ib, 64);
                float wb0 = __shfl(w0, ib, 64);
                float wb1 = __shfl(w1, ib, 64);
                float wb = (li < 4) ? wb0 : wb1;
                uint4 vb = *(const uint4*)&xl[(size_t)sb * 64 + li * 8];
                acc[0] = fmaf(bf_lo(vb.x), wb, acc[0]); acc[1] = fmaf(bf_hi(vb.x), wb, acc[1]);
                acc[2] = fmaf(bf_lo(vb.y), wb, acc[2]); acc[3] = fmaf(bf_hi(vb.y), wb, acc[3]);
                acc[4] = fmaf(bf_lo(vb.z), wb, acc[4]); acc[5] = fmaf(bf_hi(vb.z), wb, acc[5]);
                acc[6] = fmaf(bf_lo(vb.w), wb, acc[6]); acc[7] = fmaf(bf_hi(vb.w), wb, acc[7]);
            }
            if (k + 16 < cnt) {
                const int ic = k + 16 + sub;
                int   sc  = __shfl(s, ic, 64);
                float wc0 = __shfl(w0, ic, 64);
                float wc1 = __shfl(w1, ic, 64);
                float wc = (li < 4) ? wc0 : wc1;
                uint4 vc = *(const uint4*)&xl[(size_t)sc * 64 + li * 8];
                acc[0] = fmaf(bf_lo(vc.x), wc, acc[0]); acc[1] = fmaf(bf_hi(vc.x), wc, acc[1]);
                acc[2] = fmaf(bf_lo(vc.y), wc, acc[2]); acc[3] = fmaf(bf_hi(vc.y), wc, acc[3]);
                acc[4] = fmaf(bf_lo(vc.z), wc, acc[4]); acc[5] = fmaf(bf_hi(vc.z), wc, acc[5]);
                acc[6] = fmaf(bf_lo(vc.w), wc, acc[6]); acc[7] = fmaf(bf_hi(vc.w), wc, acc[7]);
            }
            if (k + 24 < cnt) {
                const int id = k + 24 + sub;
                int   sd  = __shfl(s, id, 64);
                float wd0 = __shfl(w0, id, 64);
                float wd1 = __shfl(w1, id, 64);
                float wd = (li < 4) ? wd0 : wd1;
                uint4 vd = *(const uint4*)&xl[(size_t)sd * 64 + li * 8];
                acc[0] = fmaf(bf_lo(vd.x), wd, acc[0]); acc[1] = fmaf(bf_hi(vd.x), wd, acc[1]);
                acc[2] = fmaf(bf_lo(vd.y), wd, acc[2]); acc[3] = fmaf(bf_hi(vd.y), wd, acc[3]);
                acc[4] = fmaf(bf_lo(vd.z), wd, acc[4]); acc[5] = fmaf(bf_hi(vd.z), wd, acc[5]);
                acc[6] = fmaf(bf_lo(vd.w), wd, acc[6]); acc[7] = fmaf(bf_hi(vd.w), wd, acc[7]);
            }
        }
    }
    #pragma unroll
    for (int ofs = 32; ofs >= 1; ofs >>= 1) {
        ws0 += __shfl_xor(ws0, ofs, 64);
        ws1 += __shfl_xor(ws1, ofs, 64);
    }
    #pragma unroll
    for (int ofs = 8; ofs <= 32; ofs <<= 1) {
        #pragma unroll
        for (int i = 0; i < 8; ++i) acc[i] += __shfl_xor(acc[i], ofs, 64);
    }
    {
        const float inv = 1.f / ((li < 4) ? ws0 : ws1);
        float h0 = elu_f(acc[0] * inv + b1a.x);
        float h1 = elu_f(acc[1] * inv + b1a.y);
        float h2 = elu_f(acc[2] * inv + b1a.z);
        float h3 = elu_f(acc[3] * inv + b1a.w);
        float h4 = elu_f(acc[4] * inv + b1b.x);
        float h5 = elu_f(acc[5] * inv + b1b.y);
        float h6 = elu_f(acc[6] * inv + b1b.z);
        float h7 = elu_f(acc[7] * inv + b1b.w);
        if (sub == 0) {
            float4 p0; p0.x = h0; p0.y = h1; p0.z = h2; p0.w = h3;
            float4 p1; p1.x = h4; p1.y = h5; p1.z = h6; p1.w = h7;
            *(float4*)&hbuf[wave][li * 8]     = p0;
            *(float4*)&hbuf[wave][li * 8 + 4] = p1;
        }
    }
    __syncthreads();   // hbuf ready

    float o0 = 0.f, o1 = 0.f;
    #pragma unroll
    for (int k = 0; k < C1; k += 2) {
        float2 hk = *(const float2*)&hbuf[wave][k];
        unsigned p0 = W2p[k * 64 + lane];
        unsigned p1 = W2p[(k + 1) * 64 + lane];
        o0 = fmaf(bf_lo(p0), hk.x, o0); o1 = fmaf(bf_hi(p0), hk.x, o1);
        o0 = fmaf(bf_lo(p1), hk.y, o0); o1 = fmaf(bf_hi(p1), hk.y, o1);
    }
    float ps = o0 * as2c.x + o1 * as2c.y;
    float pd = o0 * ad2c.x + o1 * ad2c.y;
    #pragma unroll
    for (int ofs = 32; ofs >= 1; ofs >>= 1) {
        ps += __shfl_xor(ps, ofs, 64);
        pd += __shfl_xor(pd, ofs, 64);
    }
    if (lane == 0) { a_s2[dst] = ps; a_d2[dst] = pd; }
    unsigned pk = (unsigned)f2bf(o0) | ((unsigned)f2bf(o1) << 16);
    xl2p[(size_t)dst * 64 + lane] = pk;
}

// ------- layer-2 attention: 16 lanes/edge, up-to-4x4 edges/iter w/ guards ----
__global__ __launch_bounds__(256) void k_attn2(
    const int* __restrict__ beg_a, const int* __restrict__ end_a,
    const unsigned* __restrict__ csr,
    const float* __restrict__ a_s, const float* __restrict__ a_d,
    const unsigned short* __restrict__ xl, float* __restrict__ out)
{
    const int wave = threadIdx.x >> 6, lane = threadIdx.x & 63;
    const int dst = blockIdx.x * 4 + wave;
    const int beg = beg_a[dst], end = end_a[dst];
    const float ad0 = a_d[dst];

    const int li = lane & 15, sub = lane >> 4;   // ch group li*8..+7; edge slot
    float acc[8];
    #pragma unroll
    for (int i = 0; i < 8; ++i) acc[i] = 0.f;
    float ws0 = 0.f;
    for (int base = beg; base < end; base += 64) {
        const int cnt = min(64, end - base);   // wave-uniform
        int s = 0; float w0 = 0.f;
        if (base + lane < end) {
            s = (int)csr[base + lane];
            float e0 = a_s[s] + ad0; e0 = e0 > 0.f ? e0 : NEG_SLOPE * e0;
            w0 = __expf(e0);
        }
        ws0 += w0;
        for (int k = 0; k < cnt; k += 16) {
            {
                const int ia = k + sub;
                int   sa = __shfl(s, ia, 64);
                float wa = __shfl(w0, ia, 64);
                uint4 va = *(const uint4*)&xl[(size_t)sa * 128 + li * 8];
                acc[0] = fmaf(bf_lo(va.x), wa, acc[0]); acc[1] = fmaf(bf_hi(va.x), wa, acc[1]);
                acc[2] = fmaf(bf_lo(va.y), wa, acc[2]); acc[3] = fmaf(bf_hi(va.y), wa, acc[3]);
                acc[4] = fmaf(bf_lo(va.z), wa, acc[4]); acc[5] = fmaf(bf_hi(va.z), wa, acc[5]);
                acc[6] = fmaf(bf_lo(va.w), wa, acc[6]); acc[7] = fmaf(bf_hi(va.w), wa, acc[7]);
            }
            if (k + 4 < cnt) {      // wave-uniform guard
                const int ib = k + 4 + sub;
                int   sb = __shfl(s, ib, 64);
                float wb = __shfl(w0, ib, 64);
                uint4 vb = *(const uint4*)&xl[(size_t)sb * 128 + li * 8];
                acc[0] = fmaf(bf_lo(vb.x), wb, acc[0]); acc[1] = fmaf(bf_hi(vb.x), wb, acc[1]);
                acc[2] = fmaf(bf_lo(vb.y), wb, acc[2]); acc[3] = fmaf(bf_hi(vb.y), wb, acc[3]);
                acc[4] = fmaf(bf_lo(vb.z), wb, acc[4]); acc[5] = fmaf(bf_hi(vb.z), wb, acc[5]);
                acc[6] = fmaf(bf_lo(vb.w), wb, acc[6]); acc[7] = fmaf(bf_hi(vb.w), wb, acc[7]);
            }
            if (k + 8 < cnt) {
                const int ic = k + 8 + sub;
                int   sc = __shfl(s, ic, 64);
                float wc = __shfl(w0, ic, 64);
                uint4 vc = *(const uint4*)&xl[(size_t)sc * 128 + li * 8];
                acc[0] = fmaf(bf_lo(vc.x), wc, acc[0]); acc[1] = fmaf(bf_hi(vc.x), wc, acc[1]);
                acc[2] = fmaf(bf_lo(vc.y), wc, acc[2]); acc[3] = fmaf(bf_hi(vc.y), wc, acc[3]);
                acc[4] = fmaf(bf_lo(vc.z), wc, acc[4]); acc[5] = fmaf(bf_hi(vc.z), wc, acc[5]);
                acc[6] = fmaf(bf_lo(vc.w), wc, acc[6]); acc[7] = fmaf(bf_hi(vc.w), wc, acc[7]);
            }
            if (k + 12 < cnt) {
                const int id = k + 12 + sub;
                int   sd = __shfl(s, id, 64);
                float wd = __shfl(w0, id, 64);
                uint4 vd = *(const uint4*)&xl[(size_t)sd * 128 + li * 8];
                acc[0] = fmaf(bf_lo(vd.x), wd, acc[0]); acc[1] = fmaf(bf_hi(vd.x), wd, acc[1]);
                acc[2] = fmaf(bf_lo(vd.y), wd, acc[2]); acc[3] = fmaf(bf_hi(vd.y), wd, acc[3]);
                acc[4] = fmaf(bf_lo(vd.z), wd, acc[4]); acc[5] = fmaf(bf_hi(vd.z), wd, acc[5]);
                acc[6] = fmaf(bf_lo(vd.w), wd, acc[6]); acc[7] = fmaf(bf_hi(vd.w), wd, acc[7]);
            }
        }
    }
    #pragma unroll
    for (int ofs = 32; ofs >= 1; ofs >>= 1)
        ws0 += __shfl_xor(ws0, ofs, 64);
    #pragma unroll
    for (int ofs = 16; ofs <= 32; ofs <<= 1) {
        #pragma unroll
        for (int i = 0; i < 8; ++i) acc[i] += __shfl_xor(acc[i], ofs, 64);
    }
    if (lane < 16) {
        const float inv = 1.f / ws0;
        float4 r0, r1;
        r0.x = acc[0]*inv; r0.y = acc[1]*inv; r0.z = acc[2]*inv; r0.w = acc[3]*inv;
        r1.x = acc[4]*inv; r1.y = acc[5]*inv; r1.z = acc[6]*inv; r1.w = acc[7]*inv;
        *(float4*)&out[(size_t)dst * 128 + li * 8]     = r0;
        *(float4*)&out[(size_t)dst * 128 + li * 8 + 4] = r1;
    }
}

// ---------------- pooling: 32 nodes/block, 2 node-lanes x 128 ch -------------
__global__ __launch_bounds__(256) void k_pool(
    const float* __restrict__ out2, const float* __restrict__ b2,
    const int* __restrict__ batch, float* __restrict__ sums, float* __restrict__ cnts)
{
    const int c    = threadIdx.x & 127;
    const int half = threadIdx.x >> 7;    // 0/1: even/odd nodes
    const int n0   = blockIdx.x * PN;
    const int nb   = n0 + half;
    if (nb >= N_NODES) return;
    const float bc = b2[c];
    float acc = 0.f;
    int cur = batch[nb], cnt = 0;
    for (int i = half; i < PN; i += 2) {
        int n = n0 + i;
        if (n >= N_NODES) break;
        int g = batch[n];
        if (g != cur) {
            atomicAdd(&sums[cur * OUT_CH + c], acc);
            if (c == 0) atomicAdd(&cnts[cur], (float)cnt);
            acc = 0.f; cnt = 0; cur = g;
        }
        acc += elu_f(out2[(size_t)n * OUT_CH + c] + bc);
        cnt++;
    }
    if (cnt > 0) {
        atomicAdd(&sums[cur * OUT_CH + c], acc);
        if (c == 0) atomicAdd(&cnts[cur], (float)cnt);
    }
}

__global__ __launch_bounds__(256) void k_final(
    const float* __restrict__ sums, const float* __restrict__ cnts,
    float* __restrict__ out)
{
    int i = blockIdx.x * 256 + threadIdx.x;
    if (i >= N_GRAPHS * OUT_CH) return;
    out[i] = sums[i] / fmaxf(cnts[i >> 7], 1.f);
}

extern "C" void kernel_launch(void* const* d_in, const int* in_sizes, int n_in,
                              void* d_out, int out_size, void* d_ws, size_t ws_size,
                              hipStream_t stream)
{
    const float* x    = (const float*)d_in[0];
    const int*   ei   = (const int*)d_in[1];
    const int*   batch= (const int*)d_in[2];
    const float* W1   = (const float*)d_in[3];
    const float* as1  = (const float*)d_in[4];
    const float* ad1  = (const float*)d_in[5];
    const float* b1   = (const float*)d_in[6];
    const float* W2   = (const float*)d_in[7];
    const float* as2  = (const float*)d_in[8];
    const float* ad2  = (const float*)d_in[9];
    const float* b2   = (const float*)d_in[10];

    float* ws = (float*)d_ws;
    size_t o = 0;
    unsigned short* xl1b = (unsigned short*)(ws + o); o += (size_t)N_NODES * C1 / 2;
    unsigned*       xl2p = (unsigned*)(ws + o);       o += (size_t)N_NODES * 64;
    float*    a_s1 = ws + o; o += (size_t)N_NODES * 2;
    float*    a_d1 = ws + o; o += (size_t)N_NODES * 2;
    float*    a_s2 = ws + o; o += (size_t)N_NODES;
    float*    a_d2 = ws + o; o += (size_t)N_NODES;
    float*    out2 = ws + o; o += (size_t)N_NODES * OUT_CH;
    unsigned* bbuf = (unsigned*)(ws + o); o += (size_t)NBUCK * BCAP;
    int*      beg  = (int*)(ws + o); o += (size_t)N_NODES;
    int*      end  = (int*)(ws + o); o += (size_t)N_NODES;
    size_t zero_start = o;
    int*      gcur = (int*)(ws + o); o += (size_t)NBUCK;
    float*    sums = ws + o;         o += (size_t)N_GRAPHS * OUT_CH;
    float*    cnts = ws + o;         o += (size_t)N_GRAPHS;
    size_t zero_bytes = (o - zero_start) * sizeof(float);
    hipMemsetAsync(ws + zero_start, 0, zero_bytes, stream);

    const int nchunks = (E_TOT + CHUNK - 1) / CHUNK;   // 202
    k_bin<<<nchunks, 256, 0, stream>>>(ei, gcur, bbuf);
    k_bsort<<<NBUCK, 256, 0, stream>>>(gcur, bbuf, beg, end);

    k_gemm1<<<N_NODES / 16, 256, 0, stream>>>(x, W1, as1, ad1, xl1b, a_s1, a_d1);
    k_attn1g2<<<N_NODES / 4, 256, 0, stream>>>(beg, end, bbuf, a_s1, a_d1, xl1b,
                                               b1, W2, as2, ad2, xl2p, a_s2, a_d2);
    k_attn2<<<N_NODES / 4, 256, 0, stream>>>(beg, end, bbuf, a_s2, a_d2,
                                             (const unsigned short*)xl2p, out2);
    k_pool<<<(N_NODES + PN - 1) / PN, 256, 0, stream>>>(out2, b2, batch, sums, cnts);
    k_final<<<(N_GRAPHS * OUT_CH + 255) / 256, 256, 0, stream>>>(sums, cnts, (float*)d_out);
}

// Round 14
// 282.259 us; speedup vs baseline: 3.5664x; 1.0589x over previous
//
#include <hip/hip_runtime.h>

#define N_NODES 50000
#define N_EDGES 1600000
#define E_TOT   (N_EDGES + N_NODES)   // 1,650,000 incl. self-loops
#define IN_CH   128
#define C1      64                    // heads(2) * hid(32)
#define OUT_CH  128
#define N_GRAPHS 64
#define NEG_SLOPE 0.2f

#define BSH   7                        // 128 dsts per bucket
#define NBUCK ((N_NODES + 127) / 128)  // 391
#define BCAP  5120                     // per-bucket region cap (mean 4220, ~14 sigma)
#define CHUNK 8192                     // edges per k_bin workgroup
#define PN    32                       // nodes per k_pool block

typedef __attribute__((ext_vector_type(8))) short bf16x8;
typedef __attribute__((ext_vector_type(4))) float f32x4;

__device__ __forceinline__ float elu_f(float v) {
    return v > 0.f ? v : (__expf(v) - 1.f);
}
__device__ __forceinline__ unsigned short f2bf(float f) {   // RNE
    unsigned u = __float_as_uint(f);
    return (unsigned short)((u + 0x7FFFu + ((u >> 16) & 1u)) >> 16);
}
__device__ __forceinline__ float bf_lo(unsigned u) { return __uint_as_float(u << 16); }
__device__ __forceinline__ float bf_hi(unsigned u) { return __uint_as_float(u & 0xFFFF0000u); }

// ---------------- GEMM1 via MFMA: xl1(bf16) = x @ W1, fused attention dots ---
__global__ __launch_bounds__(256) void k_gemm1(
    const float* __restrict__ x, const float* __restrict__ W1,
    const float* __restrict__ att_s, const float* __restrict__ att_d,
    unsigned short* __restrict__ xl1, float* __restrict__ a_s, float* __restrict__ a_d)
{
    __shared__ unsigned short W1T[64][136];  // W1^T bf16, +8 pad (17.4 KB)
    __shared__ float psA[4][16], psD[4][16];
    const int t = threadIdx.x, wave = t >> 6, lane = t & 63;
    const int quad = lane >> 4, lm = lane & 15;
    for (int i = t; i < 128 * 64; i += 256)
        W1T[i & 63][i >> 6] = f2bf(W1[i]);   // W1T[c][k] = W1[k][c]
    __syncthreads();

    const int n0 = wave * 16;
    const int c  = n0 + lm;                  // this lane's output column
    bf16x8 bfr[4];
    #pragma unroll
    for (int s = 0; s < 4; ++s)
        bfr[s] = *(const bf16x8*)&W1T[c][s * 32 + quad * 8];
    const float asc = att_s[c], adc = att_d[c];

    const int r0 = blockIdx.x * 16;
    f32x4 acc = {0.f, 0.f, 0.f, 0.f};
    #pragma unroll
    for (int s = 0; s < 4; ++s) {
        const float* xp = &x[(size_t)(r0 + lm) * 128 + s * 32 + quad * 8];
        float4 xa = *(const float4*)xp;
        float4 xb = *(const float4*)(xp + 4);
        bf16x8 afr;
        afr[0] = (short)f2bf(xa.x); afr[1] = (short)f2bf(xa.y);
        afr[2] = (short)f2bf(xa.z); afr[3] = (short)f2bf(xa.w);
        afr[4] = (short)f2bf(xb.x); afr[5] = (short)f2bf(xb.y);
        afr[6] = (short)f2bf(xb.z); afr[7] = (short)f2bf(xb.w);
        acc = __builtin_amdgcn_mfma_f32_16x16x32_bf16(afr, bfr[s], acc, 0, 0, 0);
    }
    float psv[4], pdv[4];
    #pragma unroll
    for (int r = 0; r < 4; ++r) {
        float v = acc[r];
        xl1[(size_t)(r0 + quad * 4 + r) * 64 + c] = f2bf(v);
        psv[r] = v * asc;
        pdv[r] = v * adc;
    }
    #pragma unroll
    for (int ofs = 1; ofs <= 8; ofs <<= 1) {
        #pragma unroll
        for (int r = 0; r < 4; ++r) {
            psv[r] += __shfl_xor(psv[r], ofs, 64);
            pdv[r] += __shfl_xor(pdv[r], ofs, 64);
        }
    }
    if (lm == 0) {
        #pragma unroll
        for (int r = 0; r < 4; ++r) {
            psA[wave][quad * 4 + r] = psv[r];
            psD[wave][quad * 4 + r] = pdv[r];
        }
    }
    __syncthreads();
    if (t < 32) {     // waves 0,1 -> head 0 (cols 0-31); waves 2,3 -> head 1
        const int row = t & 15, h = t >> 4;
        a_s[(size_t)(r0 + row) * 2 + h] = psA[2 * h][row] + psA[2 * h + 1][row];
        a_d[(size_t)(r0 + row) * 2 + h] = psD[2 * h][row] + psD[2 * h + 1][row];
    }
}

// ---------------- pass 1: LDS-staged binning by dst>>7 ----------------------
__global__ __launch_bounds__(256) void k_bin(
    const int* __restrict__ ei, int* __restrict__ gcur, unsigned* __restrict__ bbuf)
{
    __shared__ int cnt[512];
    __shared__ int base[NBUCK];
    __shared__ int cnt2[NBUCK];
    __shared__ int gpos[NBUCK];
    __shared__ unsigned stage[CHUNK];      // 32 KB
    __shared__ unsigned short bof[CHUNK];  // 16 KB
    const int t = threadIdx.x;
    const long long e0 = (long long)blockIdx.x * CHUNK;
    const int nE = (int)min((long long)CHUNK, (long long)E_TOT - e0);

    cnt[t] = 0; cnt[t + 256] = 0;
    for (int b = t; b < NBUCK; b += 256) cnt2[b] = 0;
    __syncthreads();

    const int per = CHUNK / 256;           // 32
    int myb[per]; unsigned mye[per];
    #pragma unroll
    for (int i = 0; i < per; ++i) {
        int idx = t + 256 * i;
        myb[i] = -1;
        if (idx < nE) {
            long long e = e0 + idx;
            int s, d;
            if (e < N_EDGES) { s = ei[e]; d = ei[N_EDGES + e]; }
            else             { s = d = (int)(e - N_EDGES); }
            myb[i] = d >> BSH;
            mye[i] = ((unsigned)(d & 127) << 17) | (unsigned)s;
            atomicAdd(&cnt[myb[i]], 1);
        }
    }
    __syncthreads();
    for (int ofs = 1; ofs < 512; ofs <<= 1) {
        int v0 = (t >= ofs) ? cnt[t - ofs] : 0;
        int v1 = cnt[t + 256 - ofs];
        __syncthreads();
        cnt[t] += v0; cnt[t + 256] += v1;
        __syncthreads();
    }
    for (int b = t; b < NBUCK; b += 256) {
        base[b] = (b == 0) ? 0 : cnt[b - 1];
        int c = cnt[b] - base[b];
        gpos[b] = (c > 0) ? atomicAdd(&gcur[b], c) : 0;
    }
    __syncthreads();
    #pragma unroll
    for (int i = 0; i < per; ++i) {
        if (myb[i] >= 0) {
            int slot = base[myb[i]] + atomicAdd(&cnt2[myb[i]], 1);
            stage[slot] = mye[i];
            bof[slot] = (unsigned short)myb[i];
        }
    }
    __syncthreads();
    for (int i = t; i < nE; i += 256) {
        int b = bof[i];
        int pos = gpos[b] + (i - base[b]);
        if (pos < BCAP)
            bbuf[(size_t)b * BCAP + pos] = stage[i];
    }
}

// ---------------- pass 2: per-bucket counting sort, emits beg/end -----------
__global__ __launch_bounds__(256) void k_bsort(
    const int* __restrict__ gcur, unsigned* __restrict__ bbuf,
    int* __restrict__ beg, int* __restrict__ end)
{
    __shared__ unsigned est[BCAP];   // 20 KB
    __shared__ unsigned sst[BCAP];   // 20 KB
    __shared__ int c[128], lbase[128], c2[128];
    const int b = blockIdx.x, t = threadIdx.x;
    const int n = min(gcur[b], BCAP);
    unsigned* reg = bbuf + (size_t)b * BCAP;
    for (int i = t; i < n; i += 256) est[i] = reg[i];
    if (t < 128) { c[t] = 0; c2[t] = 0; }
    __syncthreads();
    for (int i = t; i < n; i += 256) atomicAdd(&c[est[i] >> 17], 1);
    __syncthreads();
    for (int ofs = 1; ofs < 128; ofs <<= 1) {
        int v = (t < 128 && t >= ofs) ? c[t - ofs] : 0;
        __syncthreads();
        if (t < 128) c[t] += v;
        __syncthreads();
    }
    if (t < 128) {
        lbase[t] = (t == 0) ? 0 : c[t - 1];
        int dst = (b << BSH) + t;
        if (dst < N_NODES) {
            beg[dst] = b * BCAP + lbase[t];
            end[dst] = b * BCAP + c[t];
        }
    }
    __syncthreads();
    for (int i = t; i < n; i += 256) {
        unsigned v = est[i];
        int dl = (int)(v >> 17);
        int pos = lbase[dl] + atomicAdd(&c2[dl], 1);
        sst[pos] = v & 0x1FFFFu;
    }
    __syncthreads();
    for (int i = t; i < n; i += 256) reg[i] = sst[i];
}

// ------- layer-1 attention: softmax-aggregate, h(bf16) out, no Phase B -------
__global__ __launch_bounds__(256) void k_attn1(
    const int* __restrict__ beg_a, const int* __restrict__ end_a,
    const unsigned* __restrict__ csr,
    const float* __restrict__ a_s, const float* __restrict__ a_d,
    const unsigned short* __restrict__ xl,
    const float* __restrict__ b1,
    unsigned short* __restrict__ hout)    // [N][64] bf16: elu(aggregate + b1)
{
    const int wave = threadIdx.x >> 6, lane = threadIdx.x & 63;
    const int dst = blockIdx.x * 4 + wave;           // grid = 12500
    const int beg = beg_a[dst], end = end_a[dst];
    const float ad0 = a_d[dst * 2], ad1 = a_d[dst * 2 + 1];
    const int li = lane & 7, sub = lane >> 3;
    const float4 b1a = *(const float4*)&b1[li * 8];
    const float4 b1b = *(const float4*)&b1[li * 8 + 4];

    float acc[8];
    #pragma unroll
    for (int i = 0; i < 8; ++i) acc[i] = 0.f;
    float ws0 = 0.f, ws1 = 0.f;
    for (int base = beg; base < end; base += 64) {
        const int cnt = min(64, end - base);   // wave-uniform
        int s = 0; float w0 = 0.f, w1 = 0.f;
        if (base + lane < end) {
            s = (int)csr[base + lane];
            float e0 = a_s[s * 2] + ad0;     e0 = e0 > 0.f ? e0 : NEG_SLOPE * e0;
            float e1 = a_s[s * 2 + 1] + ad1; e1 = e1 > 0.f ? e1 : NEG_SLOPE * e1;
            w0 = __expf(e0);
            w1 = __expf(e1);
        }
        ws0 += w0; ws1 += w1;
        for (int k = 0; k < cnt; k += 32) {
            {
                const int ia = k + sub;
                int   sa  = __shfl(s, ia, 64);   // uniform shuffles, select after
                float wa0 = __shfl(w0, ia, 64);
                float wa1 = __shfl(w1, ia, 64);
                float wa = (li < 4) ? wa0 : wa1;
                uint4 va = *(const uint4*)&xl[(size_t)sa * 64 + li * 8];
                acc[0] = fmaf(bf_lo(va.x), wa, acc[0]); acc[1] = fmaf(bf_hi(va.x), wa, acc[1]);
                acc[2] = fmaf(bf_lo(va.y), wa, acc[2]); acc[3] = fmaf(bf_hi(va.y), wa, acc[3]);
                acc[4] = fmaf(bf_lo(va.z), wa, acc[4]); acc[5] = fmaf(bf_hi(va.z), wa, acc[5]);
                acc[6] = fmaf(bf_lo(va.w), wa, acc[6]); acc[7] = fmaf(bf_hi(va.w), wa, acc[7]);
            }
            if (k + 8 < cnt) {
                const int ib = k + 8 + sub;
                int   sb  = __shfl(s, ib, 64);
                float wb0 = __shfl(w0, ib, 64);
                float wb1 = __shfl(w1, ib, 64);
                float wb = (li < 4) ? wb0 : wb1;
                uint4 vb = *(const uint4*)&xl[(size_t)sb * 64 + li * 8];
                acc[0] = fmaf(bf_lo(vb.x), wb, acc[0]); acc[1] = fmaf(bf_hi(vb.x), wb, acc[1]);
                acc[2] = fmaf(bf_lo(vb.y), wb, acc[2]); acc[3] = fmaf(bf_hi(vb.y), wb, acc[3]);
                acc[4] = fmaf(bf_lo(vb.z), wb, acc[4]); acc[5] = fmaf(bf_hi(vb.z), wb, acc[5]);
                acc[6] = fmaf(bf_lo(vb.w), wb, acc[6]); acc[7] = fmaf(bf_hi(vb.w), wb, acc[7]);
            }
            if (k + 16 < cnt) {
                const int ic = k + 16 + sub;
                int   sc  = __shfl(s, ic, 64);
                float wc0 = __shfl(w0, ic, 64);
                float wc1 = __shfl(w1, ic, 64);
                float wc = (li < 4) ? wc0 : wc1;
                uint4 vc = *(const uint4*)&xl[(size_t)sc * 64 + li * 8];
                acc[0] = fmaf(bf_lo(vc.x), wc, acc[0]); acc[1] = fmaf(bf_hi(vc.x), wc, acc[1]);
                acc[2] = fmaf(bf_lo(vc.y), wc, acc[2]); acc[3] = fmaf(bf_hi(vc.y), wc, acc[3]);
                acc[4] = fmaf(bf_lo(vc.z), wc, acc[4]); acc[5] = fmaf(bf_hi(vc.z), wc, acc[5]);
                acc[6] = fmaf(bf_lo(vc.w), wc, acc[6]); acc[7] = fmaf(bf_hi(vc.w), wc, acc[7]);
            }
            if (k + 24 < cnt) {
                const int id = k + 24 + sub;
                int   sd  = __shfl(s, id, 64);
                float wd0 = __shfl(w0, id, 64);
                float wd1 = __shfl(w1, id, 64);
                float wd = (li < 4) ? wd0 : wd1;
                uint4 vd = *(const uint4*)&xl[(size_t)sd * 64 + li * 8];
                acc[0] = fmaf(bf_lo(vd.x), wd, acc[0]); acc[1] = fmaf(bf_hi(vd.x), wd, acc[1]);
                acc[2] = fmaf(bf_lo(vd.y), wd, acc[2]); acc[3] = fmaf(bf_hi(vd.y), wd, acc[3]);
                acc[4] = fmaf(bf_lo(vd.z), wd, acc[4]); acc[5] = fmaf(bf_hi(vd.z), wd, acc[5]);
                acc[6] = fmaf(bf_lo(vd.w), wd, acc[6]); acc[7] = fmaf(bf_hi(vd.w), wd, acc[7]);
            }
        }
    }
    #pragma unroll
    for (int ofs = 32; ofs >= 1; ofs >>= 1) {
        ws0 += __shfl_xor(ws0, ofs, 64);
        ws1 += __shfl_xor(ws1, ofs, 64);
    }
    #pragma unroll
    for (int ofs = 8; ofs <= 32; ofs <<= 1) {
        #pragma unroll
        for (int i = 0; i < 8; ++i) acc[i] += __shfl_xor(acc[i], ofs, 64);
    }
    if (sub == 0) {
        const float inv = 1.f / ((li < 4) ? ws0 : ws1);
        float h0 = elu_f(acc[0] * inv + b1a.x);
        float h1 = elu_f(acc[1] * inv + b1a.y);
        float h2 = elu_f(acc[2] * inv + b1a.z);
        float h3 = elu_f(acc[3] * inv + b1a.w);
        float h4 = elu_f(acc[4] * inv + b1b.x);
        float h5 = elu_f(acc[5] * inv + b1b.y);
        float h6 = elu_f(acc[6] * inv + b1b.z);
        float h7 = elu_f(acc[7] * inv + b1b.w);
        uint4 p;
        p.x = (unsigned)f2bf(h0) | ((unsigned)f2bf(h1) << 16);
        p.y = (unsigned)f2bf(h2) | ((unsigned)f2bf(h3) << 16);
        p.z = (unsigned)f2bf(h4) | ((unsigned)f2bf(h5) << 16);
        p.w = (unsigned)f2bf(h6) | ((unsigned)f2bf(h7) << 16);
        *(uint4*)&hout[(size_t)dst * 64 + li * 8] = p;
    }
}

// ---------------- GEMM2 via MFMA: xl2(bf16) = h @ W2, fused attention dots ---
// Block = 16 rows (3125 blocks). Wave w owns col-tiles 2w, 2w+1 (32 cols).
__global__ __launch_bounds__(256) void k_gemm2m(
    const unsigned short* __restrict__ h, const float* __restrict__ W2,
    const float* __restrict__ att_s, const float* __restrict__ att_d,
    unsigned short* __restrict__ xl2, float* __restrict__ a_s, float* __restrict__ a_d)
{
    __shared__ unsigned short W2T[128][72];  // W2^T bf16, pad 72 (18.4 KB)
    __shared__ float psA[4][16], psD[4][16];
    const int t = threadIdx.x, wave = t >> 6, lane = t & 63;
    const int quad = lane >> 4, lm = lane & 15;
    for (int i = t; i < 64 * 128; i += 256)
        W2T[i & 127][i >> 7] = f2bf(W2[i]);  // W2T[c][k] = W2[k][c]
    __syncthreads();

    const int c0 = wave * 32 + lm;           // col for ct=0
    const int c1 = c0 + 16;                  // col for ct=1
    bf16x8 bfr0[2], bfr1[2];
    #pragma unroll
    for (int s = 0; s < 2; ++s) {
        bfr0[s] = *(const bf16x8*)&W2T[c0][s * 32 + quad * 8];
        bfr1[s] = *(const bf16x8*)&W2T[c1][s * 32 + quad * 8];
    }
    const float as0 = att_s[c0], as1 = att_s[c1];
    const float ad0 = att_d[c0], ad1 = att_d[c1];

    const int r0 = blockIdx.x * 16;
    f32x4 acc0 = {0.f, 0.f, 0.f, 0.f}, acc1 = {0.f, 0.f, 0.f, 0.f};
    #pragma unroll
    for (int s = 0; s < 2; ++s) {
        bf16x8 afr = *(const bf16x8*)&h[(size_t)(r0 + lm) * 64 + s * 32 + quad * 8];
        acc0 = __builtin_amdgcn_mfma_f32_16x16x32_bf16(afr, bfr0[s], acc0, 0, 0, 0);
        acc1 = __builtin_amdgcn_mfma_f32_16x16x32_bf16(afr, bfr1[s], acc1, 0, 0, 0);
    }
    float psv[4], pdv[4];
    #pragma unroll
    for (int r = 0; r < 4; ++r) {
        float v0 = acc0[r], v1 = acc1[r];
        const size_t row = (size_t)(r0 + quad * 4 + r) * 128;
        xl2[row + c0] = f2bf(v0);
        xl2[row + c1] = f2bf(v1);
        psv[r] = v0 * as0 + v1 * as1;
        pdv[r] = v0 * ad0 + v1 * ad1;
    }
    #pragma unroll
    for (int ofs = 1; ofs <= 8; ofs <<= 1) {
        #pragma unroll
        for (int r = 0; r < 4; ++r) {
            psv[r] += __shfl_xor(psv[r], ofs, 64);
            pdv[r] += __shfl_xor(pdv[r], ofs, 64);
        }
    }
    if (lm == 0) {
        #pragma unroll
        for (int r = 0; r < 4; ++r) {
            psA[wave][quad * 4 + r] = psv[r];
            psD[wave][quad * 4 + r] = pdv[r];
        }
    }
    __syncthreads();
    if (t < 16) {
        a_s[r0 + t] = psA[0][t] + psA[1][t] + psA[2][t] + psA[3][t];
        a_d[r0 + t] = psD[0][t] + psD[1][t] + psD[2][t] + psD[3][t];
    }
}

// ------- layer-2 attention: 16 lanes/edge, up-to-4x4 edges/iter w/ guards ----
__global__ __launch_bounds__(256) void k_attn2(
    const int* __restrict__ beg_a, const int* __restrict__ end_a,
    const unsigned* __restrict__ csr,
    const float* __restrict__ a_s, const float* __restrict__ a_d,
    const unsigned short* __restrict__ xl, float* __restrict__ out)
{
    const int wave = threadIdx.x >> 6, lane = threadIdx.x & 63;
    const int dst = blockIdx.x * 4 + wave;
    const int beg = beg_a[dst], end = end_a[dst];
    const float ad0 = a_d[dst];

    const int li = lane & 15, sub = lane >> 4;
    float acc[8];
    #pragma unroll
    for (int i = 0; i < 8; ++i) acc[i] = 0.f;
    float ws0 = 0.f;
    for (int base = beg; base < end; base += 64) {
        const int cnt = min(64, end - base);   // wave-uniform
        int s = 0; float w0 = 0.f;
        if (base + lane < end) {
            s = (int)csr[base + lane];
            float e0 = a_s[s] + ad0; e0 = e0 > 0.f ? e0 : NEG_SLOPE * e0;
            w0 = __expf(e0);
        }
        ws0 += w0;
        for (int k = 0; k < cnt; k += 16) {
            {
                const int ia = k + sub;
                int   sa = __shfl(s, ia, 64);
                float wa = __shfl(w0, ia, 64);
                uint4 va = *(const uint4*)&xl[(size_t)sa * 128 + li * 8];
                acc[0] = fmaf(bf_lo(va.x), wa, acc[0]); acc[1] = fmaf(bf_hi(va.x), wa, acc[1]);
                acc[2] = fmaf(bf_lo(va.y), wa, acc[2]); acc[3] = fmaf(bf_hi(va.y), wa, acc[3]);
                acc[4] = fmaf(bf_lo(va.z), wa, acc[4]); acc[5] = fmaf(bf_hi(va.z), wa, acc[5]);
                acc[6] = fmaf(bf_lo(va.w), wa, acc[6]); acc[7] = fmaf(bf_hi(va.w), wa, acc[7]);
            }
            if (k + 4 < cnt) {
                const int ib = k + 4 + sub;
                int   sb = __shfl(s, ib, 64);
                float wb = __shfl(w0, ib, 64);
                uint4 vb = *(const uint4*)&xl[(size_t)sb * 128 + li * 8];
                acc[0] = fmaf(bf_lo(vb.x), wb, acc[0]); acc[1] = fmaf(bf_hi(vb.x), wb, acc[1]);
                acc[2] = fmaf(bf_lo(vb.y), wb, acc[2]); acc[3] = fmaf(bf_hi(vb.y), wb, acc[3]);
                acc[4] = fmaf(bf_lo(vb.z), wb, acc[4]); acc[5] = fmaf(bf_hi(vb.z), wb, acc[5]);
                acc[6] = fmaf(bf_lo(vb.w), wb, acc[6]); acc[7] = fmaf(bf_hi(vb.w), wb, acc[7]);
            }
            if (k + 8 < cnt) {
                const int ic = k + 8 + sub;
                int   sc = __shfl(s, ic, 64);
                float wc = __shfl(w0, ic, 64);
                uint4 vc = *(const uint4*)&xl[(size_t)sc * 128 + li * 8];
                acc[0] = fmaf(bf_lo(vc.x), wc, acc[0]); acc[1] = fmaf(bf_hi(vc.x), wc, acc[1]);
                acc[2] = fmaf(bf_lo(vc.y), wc, acc[2]); acc[3] = fmaf(bf_hi(vc.y), wc, acc[3]);
                acc[4] = fmaf(bf_lo(vc.z), wc, acc[4]); acc[5] = fmaf(bf_hi(vc.z), wc, acc[5]);
                acc[6] = fmaf(bf_lo(vc.w), wc, acc[6]); acc[7] = fmaf(bf_hi(vc.w), wc, acc[7]);
            }
            if (k + 12 < cnt) {
                const int id = k + 12 + sub;
                int   sd = __shfl(s, id, 64);
                float wd = __shfl(w0, id, 64);
                uint4 vd = *(const uint4*)&xl[(size_t)sd * 128 + li * 8];
                acc[0] = fmaf(bf_lo(vd.x), wd, acc[0]); acc[1] = fmaf(bf_hi(vd.x), wd, acc[1]);
                acc[2] = fmaf(bf_lo(vd.y), wd, acc[2]); acc[3] = fmaf(bf_hi(vd.y), wd, acc[3]);
                acc[4] = fmaf(bf_lo(vd.z), wd, acc[4]); acc[5] = fmaf(bf_hi(vd.z), wd, acc[5]);
                acc[6] = fmaf(bf_lo(vd.w), wd, acc[6]); acc[7] = fmaf(bf_hi(vd.w), wd, acc[7]);
            }
        }
    }
    #pragma unroll
    for (int ofs = 32; ofs >= 1; ofs >>= 1)
        ws0 += __shfl_xor(ws0, ofs, 64);
    #pragma unroll
    for (int ofs = 16; ofs <= 32; ofs <<= 1) {
        #pragma unroll
        for (int i = 0; i < 8; ++i) acc[i] += __shfl_xor(acc[i], ofs, 64);
    }
    if (lane < 16) {
        const float inv = 1.f / ws0;
        float4 r0, r1;
        r0.x = acc[0]*inv; r0.y = acc[1]*inv; r0.z = acc[2]*inv; r0.w = acc[3]*inv;
        r1.x = acc[4]*inv; r1.y = acc[5]*inv; r1.z = acc[6]*inv; r1.w = acc[7]*inv;
        *(float4*)&out[(size_t)dst * 128 + li * 8]     = r0;
        *(float4*)&out[(size_t)dst * 128 + li * 8 + 4] = r1;
    }
}

// ---------------- pooling: 32 nodes/block, 2 node-lanes x 128 ch -------------
__global__ __launch_bounds__(256) void k_pool(
    const float* __restrict__ out2, const float* __restrict__ b2,
    const int* __restrict__ batch, float* __restrict__ sums, float* __restrict__ cnts)
{
    const int c    = threadIdx.x & 127;
    const int half = threadIdx.x >> 7;
    const int n0   = blockIdx.x * PN;
    const int nb   = n0 + half;
    if (nb >= N_NODES) return;
    const float bc = b2[c];
    float acc = 0.f;
    int cur = batch[nb], cnt = 0;
    for (int i = half; i < PN; i += 2) {
        int n = n0 + i;
        if (n >= N_NODES) break;
        int g = batch[n];
        if (g != cur) {
            atomicAdd(&sums[cur * OUT_CH + c], acc);
            if (c == 0) atomicAdd(&cnts[cur], (float)cnt);
            acc = 0.f; cnt = 0; cur = g;
        }
        acc += elu_f(out2[(size_t)n * OUT_CH + c] + bc);
        cnt++;
    }
    if (cnt > 0) {
        atomicAdd(&sums[cur * OUT_CH + c], acc);
        if (c == 0) atomicAdd(&cnts[cur], (float)cnt);
    }
}

__global__ __launch_bounds__(256) void k_final(
    const float* __restrict__ sums, const float* __restrict__ cnts,
    float* __restrict__ out)
{
    int i = blockIdx.x * 256 + threadIdx.x;
    if (i >= N_GRAPHS * OUT_CH) return;
    out[i] = sums[i] / fmaxf(cnts[i >> 7], 1.f);
}

extern "C" void kernel_launch(void* const* d_in, const int* in_sizes, int n_in,
                              void* d_out, int out_size, void* d_ws, size_t ws_size,
                              hipStream_t stream)
{
    const float* x    = (const float*)d_in[0];
    const int*   ei   = (const int*)d_in[1];
    const int*   batch= (const int*)d_in[2];
    const float* W1   = (const float*)d_in[3];
    const float* as1  = (const float*)d_in[4];
    const float* ad1  = (const float*)d_in[5];
    const float* b1   = (const float*)d_in[6];
    const float* W2   = (const float*)d_in[7];
    const float* as2  = (const float*)d_in[8];
    const float* ad2  = (const float*)d_in[9];
    const float* b2   = (const float*)d_in[10];

    float* ws = (float*)d_ws;
    size_t o = 0;
    unsigned short* xl1b = (unsigned short*)(ws + o); o += (size_t)N_NODES * C1 / 2;
    unsigned short* hbuf = (unsigned short*)(ws + o); o += (size_t)N_NODES * C1 / 2;
    unsigned short* xl2b = (unsigned short*)(ws + o); o += (size_t)N_NODES * OUT_CH / 2;
    float*    a_s1 = ws + o; o += (size_t)N_NODES * 2;
    float*    a_d1 = ws + o; o += (size_t)N_NODES * 2;
    float*    a_s2 = ws + o; o += (size_t)N_NODES;
    float*    a_d2 = ws + o; o += (size_t)N_NODES;
    float*    out2 = ws + o; o += (size_t)N_NODES * OUT_CH;
    unsigned* bbuf = (unsigned*)(ws + o); o += (size_t)NBUCK * BCAP;
    int*      beg  = (int*)(ws + o); o += (size_t)N_NODES;
    int*      end  = (int*)(ws + o); o += (size_t)N_NODES;
    size_t zero_start = o;
    int*      gcur = (int*)(ws + o); o += (size_t)NBUCK;
    float*    sums = ws + o;         o += (size_t)N_GRAPHS * OUT_CH;
    float*    cnts = ws + o;         o += (size_t)N_GRAPHS;
    size_t zero_bytes = (o - zero_start) * sizeof(float);
    hipMemsetAsync(ws + zero_start, 0, zero_bytes, stream);

    const int nchunks = (E_TOT + CHUNK - 1) / CHUNK;   // 202
    k_bin<<<nchunks, 256, 0, stream>>>(ei, gcur, bbuf);
    k_bsort<<<NBUCK, 256, 0, stream>>>(gcur, bbuf, beg, end);

    k_gemm1<<<N_NODES / 16, 256, 0, stream>>>(x, W1, as1, ad1, xl1b, a_s1, a_d1);
    k_attn1<<<N_NODES / 4, 256, 0, stream>>>(beg, end, bbuf, a_s1, a_d1, xl1b, b1, hbuf);
    k_gemm2m<<<(N_NODES + 15) / 16, 256, 0, stream>>>(hbuf, W2, as2, ad2, xl2b, a_s2, a_d2);
    k_attn2<<<N_NODES / 4, 256, 0, stream>>>(beg, end, bbuf, a_s2, a_d2, xl2b, out2);
    k_pool<<<(N_NODES + PN - 1) / PN, 256, 0, stream>>>(out2, b2, batch, sums, cnts);
    k_final<<<(N_GRAPHS * OUT_CH + 255) / 256, 256, 0, stream>>>(sums, cnts, (float*)d_out);
}

// Round 15
// 271.039 us; speedup vs baseline: 3.7141x; 1.0414x over previous
//
#include <hip/hip_runtime.h>

#define N_NODES 50000
#define N_EDGES 1600000
#define E_TOT   (N_EDGES + N_NODES)   // 1,650,000 incl. self-loops
#define IN_CH   128
#define C1      64                    // heads(2) * hid(32)
#define OUT_CH  128
#define N_GRAPHS 64
#define NEG_SLOPE 0.2f

#define BSH   7                        // 128 dsts per bucket
#define NBUCK ((N_NODES + 127) / 128)  // 391
#define BCAP  5120                     // per-bucket region cap (mean 4220, ~14 sigma)
#define CHUNK 8192                     // edges per k_bin workgroup
#define PN    32                       // nodes per k_pool block

typedef __attribute__((ext_vector_type(8))) short bf16x8;
typedef __attribute__((ext_vector_type(4))) float f32x4;
typedef __attribute__((ext_vector_type(2))) float f32x2;

__device__ __forceinline__ float elu_f(float v) {
    return v > 0.f ? v : (__expf(v) - 1.f);
}
__device__ __forceinline__ unsigned short f2bf(float f) {   // RNE
    unsigned u = __float_as_uint(f);
    return (unsigned short)((u + 0x7FFFu + ((u >> 16) & 1u)) >> 16);
}
__device__ __forceinline__ float bf_lo(unsigned u) { return __uint_as_float(u << 16); }
__device__ __forceinline__ float bf_hi(unsigned u) { return __uint_as_float(u & 0xFFFF0000u); }
__device__ __forceinline__ unsigned char f2fp8(float v) {   // OCP e4m3 via HW cvt
    return (unsigned char)(__builtin_amdgcn_cvt_pk_fp8_f32(v, v, 0, false) & 0xFF);
}

// ---------------- GEMM1 via MFMA: xl1(bf16) = x @ W1, fused attention dots ---
__global__ __launch_bounds__(256) void k_gemm1(
    const float* __restrict__ x, const float* __restrict__ W1,
    const float* __restrict__ att_s, const float* __restrict__ att_d,
    unsigned short* __restrict__ xl1, float* __restrict__ a_s, float* __restrict__ a_d)
{
    __shared__ unsigned short W1T[64][136];  // W1^T bf16, +8 pad (17.4 KB)
    __shared__ float psA[4][16], psD[4][16];
    const int t = threadIdx.x, wave = t >> 6, lane = t & 63;
    const int quad = lane >> 4, lm = lane & 15;
    for (int i = t; i < 128 * 64; i += 256)
        W1T[i & 63][i >> 6] = f2bf(W1[i]);   // W1T[c][k] = W1[k][c]
    __syncthreads();

    const int n0 = wave * 16;
    const int c  = n0 + lm;                  // this lane's output column
    bf16x8 bfr[4];
    #pragma unroll
    for (int s = 0; s < 4; ++s)
        bfr[s] = *(const bf16x8*)&W1T[c][s * 32 + quad * 8];
    const float asc = att_s[c], adc = att_d[c];

    const int r0 = blockIdx.x * 16;
    f32x4 acc = {0.f, 0.f, 0.f, 0.f};
    #pragma unroll
    for (int s = 0; s < 4; ++s) {
        const float* xp = &x[(size_t)(r0 + lm) * 128 + s * 32 + quad * 8];
        float4 xa = *(const float4*)xp;
        float4 xb = *(const float4*)(xp + 4);
        bf16x8 afr;
        afr[0] = (short)f2bf(xa.x); afr[1] = (short)f2bf(xa.y);
        afr[2] = (short)f2bf(xa.z); afr[3] = (short)f2bf(xa.w);
        afr[4] = (short)f2bf(xb.x); afr[5] = (short)f2bf(xb.y);
        afr[6] = (short)f2bf(xb.z); afr[7] = (short)f2bf(xb.w);
        acc = __builtin_amdgcn_mfma_f32_16x16x32_bf16(afr, bfr[s], acc, 0, 0, 0);
    }
    float psv[4], pdv[4];
    #pragma unroll
    for (int r = 0; r < 4; ++r) {
        float v = acc[r];
        xl1[(size_t)(r0 + quad * 4 + r) * 64 + c] = f2bf(v);
        psv[r] = v * asc;
        pdv[r] = v * adc;
    }
    #pragma unroll
    for (int ofs = 1; ofs <= 8; ofs <<= 1) {
        #pragma unroll
        for (int r = 0; r < 4; ++r) {
            psv[r] += __shfl_xor(psv[r], ofs, 64);
            pdv[r] += __shfl_xor(pdv[r], ofs, 64);
        }
    }
    if (lm == 0) {
        #pragma unroll
        for (int r = 0; r < 4; ++r) {
            psA[wave][quad * 4 + r] = psv[r];
            psD[wave][quad * 4 + r] = pdv[r];
        }
    }
    __syncthreads();
    if (t < 32) {
        const int row = t & 15, h = t >> 4;
        a_s[(size_t)(r0 + row) * 2 + h] = psA[2 * h][row] + psA[2 * h + 1][row];
        a_d[(size_t)(r0 + row) * 2 + h] = psD[2 * h][row] + psD[2 * h + 1][row];
    }
}

// ---------------- pass 1: LDS-staged binning by dst>>7 ----------------------
__global__ __launch_bounds__(256) void k_bin(
    const int* __restrict__ ei, int* __restrict__ gcur, unsigned* __restrict__ bbuf)
{
    __shared__ int cnt[512];
    __shared__ int base[NBUCK];
    __shared__ int cnt2[NBUCK];
    __shared__ int gpos[NBUCK];
    __shared__ unsigned stage[CHUNK];      // 32 KB
    __shared__ unsigned short bof[CHUNK];  // 16 KB
    const int t = threadIdx.x;
    const long long e0 = (long long)blockIdx.x * CHUNK;
    const int nE = (int)min((long long)CHUNK, (long long)E_TOT - e0);

    cnt[t] = 0; cnt[t + 256] = 0;
    for (int b = t; b < NBUCK; b += 256) cnt2[b] = 0;
    __syncthreads();

    const int per = CHUNK / 256;           // 32
    int myb[per]; unsigned mye[per];
    #pragma unroll
    for (int i = 0; i < per; ++i) {
        int idx = t + 256 * i;
        myb[i] = -1;
        if (idx < nE) {
            long long e = e0 + idx;
            int s, d;
            if (e < N_EDGES) { s = ei[e]; d = ei[N_EDGES + e]; }
            else             { s = d = (int)(e - N_EDGES); }
            myb[i] = d >> BSH;
            mye[i] = ((unsigned)(d & 127) << 17) | (unsigned)s;
            atomicAdd(&cnt[myb[i]], 1);
        }
    }
    __syncthreads();
    for (int ofs = 1; ofs < 512; ofs <<= 1) {
        int v0 = (t >= ofs) ? cnt[t - ofs] : 0;
        int v1 = cnt[t + 256 - ofs];
        __syncthreads();
        cnt[t] += v0; cnt[t + 256] += v1;
        __syncthreads();
    }
    for (int b = t; b < NBUCK; b += 256) {
        base[b] = (b == 0) ? 0 : cnt[b - 1];
        int c = cnt[b] - base[b];
        gpos[b] = (c > 0) ? atomicAdd(&gcur[b], c) : 0;
    }
    __syncthreads();
    #pragma unroll
    for (int i = 0; i < per; ++i) {
        if (myb[i] >= 0) {
            int slot = base[myb[i]] + atomicAdd(&cnt2[myb[i]], 1);
            stage[slot] = mye[i];
            bof[slot] = (unsigned short)myb[i];
        }
    }
    __syncthreads();
    for (int i = t; i < nE; i += 256) {
        int b = bof[i];
        int pos = gpos[b] + (i - base[b]);
        if (pos < BCAP)
            bbuf[(size_t)b * BCAP + pos] = stage[i];
    }
}

// ---------------- pass 2: per-bucket counting sort, emits beg/end -----------
__global__ __launch_bounds__(256) void k_bsort(
    const int* __restrict__ gcur, unsigned* __restrict__ bbuf,
    int* __restrict__ beg, int* __restrict__ end)
{
    __shared__ unsigned est[BCAP];   // 20 KB
    __shared__ unsigned sst[BCAP];   // 20 KB
    __shared__ int c[128], lbase[128], c2[128];
    const int b = blockIdx.x, t = threadIdx.x;
    const int n = min(gcur[b], BCAP);
    unsigned* reg = bbuf + (size_t)b * BCAP;
    for (int i = t; i < n; i += 256) est[i] = reg[i];
    if (t < 128) { c[t] = 0; c2[t] = 0; }
    __syncthreads();
    for (int i = t; i < n; i += 256) atomicAdd(&c[est[i] >> 17], 1);
    __syncthreads();
    for (int ofs = 1; ofs < 128; ofs <<= 1) {
        int v = (t < 128 && t >= ofs) ? c[t - ofs] : 0;
        __syncthreads();
        if (t < 128) c[t] += v;
        __syncthreads();
    }
    if (t < 128) {
        lbase[t] = (t == 0) ? 0 : c[t - 1];
        int dst = (b << BSH) + t;
        if (dst < N_NODES) {
            beg[dst] = b * BCAP + lbase[t];
            end[dst] = b * BCAP + c[t];
        }
    }
    __syncthreads();
    for (int i = t; i < n; i += 256) {
        unsigned v = est[i];
        int dl = (int)(v >> 17);
        int pos = lbase[dl] + atomicAdd(&c2[dl], 1);
        sst[pos] = v & 0x1FFFFu;
    }
    __syncthreads();
    for (int i = t; i < n; i += 256) reg[i] = sst[i];
}

// ------- layer-1 attention: softmax-aggregate, h(bf16) out -------------------
__global__ __launch_bounds__(256) void k_attn1(
    const int* __restrict__ beg_a, const int* __restrict__ end_a,
    const unsigned* __restrict__ csr,
    const float* __restrict__ a_s, const float* __restrict__ a_d,
    const unsigned short* __restrict__ xl,
    const float* __restrict__ b1,
    unsigned short* __restrict__ hout)    // [N][64] bf16: elu(aggregate + b1)
{
    const int wave = threadIdx.x >> 6, lane = threadIdx.x & 63;
    const int dst = blockIdx.x * 4 + wave;           // grid = 12500
    const int beg = beg_a[dst], end = end_a[dst];
    const float ad0 = a_d[dst * 2], ad1 = a_d[dst * 2 + 1];
    const int li = lane & 7, sub = lane >> 3;
    const float4 b1a = *(const float4*)&b1[li * 8];
    const float4 b1b = *(const float4*)&b1[li * 8 + 4];

    float acc[8];
    #pragma unroll
    for (int i = 0; i < 8; ++i) acc[i] = 0.f;
    float ws0 = 0.f, ws1 = 0.f;
    for (int base = beg; base < end; base += 64) {
        const int cnt = min(64, end - base);   // wave-uniform
        int s = 0; float w0 = 0.f, w1 = 0.f;
        if (base + lane < end) {
            s = (int)csr[base + lane];
            float e0 = a_s[s * 2] + ad0;     e0 = e0 > 0.f ? e0 : NEG_SLOPE * e0;
            float e1 = a_s[s * 2 + 1] + ad1; e1 = e1 > 0.f ? e1 : NEG_SLOPE * e1;
            w0 = __expf(e0);
            w1 = __expf(e1);
        }
        ws0 += w0; ws1 += w1;
        for (int k = 0; k < cnt; k += 32) {
            {
                const int ia = k + sub;
                int   sa  = __shfl(s, ia, 64);   // uniform shuffles, select after
                float wa0 = __shfl(w0, ia, 64);
                float wa1 = __shfl(w1, ia, 64);
                float wa = (li < 4) ? wa0 : wa1;
                uint4 va = *(const uint4*)&xl[(size_t)sa * 64 + li * 8];
                acc[0] = fmaf(bf_lo(va.x), wa, acc[0]); acc[1] = fmaf(bf_hi(va.x), wa, acc[1]);
                acc[2] = fmaf(bf_lo(va.y), wa, acc[2]); acc[3] = fmaf(bf_hi(va.y), wa, acc[3]);
                acc[4] = fmaf(bf_lo(va.z), wa, acc[4]); acc[5] = fmaf(bf_hi(va.z), wa, acc[5]);
                acc[6] = fmaf(bf_lo(va.w), wa, acc[6]); acc[7] = fmaf(bf_hi(va.w), wa, acc[7]);
            }
            if (k + 8 < cnt) {
                const int ib = k + 8 + sub;
                int   sb  = __shfl(s, ib, 64);
                float wb0 = __shfl(w0, ib, 64);
                float wb1 = __shfl(w1, ib, 64);
                float wb = (li < 4) ? wb0 : wb1;
                uint4 vb = *(const uint4*)&xl[(size_t)sb * 64 + li * 8];
                acc[0] = fmaf(bf_lo(vb.x), wb, acc[0]); acc[1] = fmaf(bf_hi(vb.x), wb, acc[1]);
                acc[2] = fmaf(bf_lo(vb.y), wb, acc[2]); acc[3] = fmaf(bf_hi(vb.y), wb, acc[3]);
                acc[4] = fmaf(bf_lo(vb.z), wb, acc[4]); acc[5] = fmaf(bf_hi(vb.z), wb, acc[5]);
                acc[6] = fmaf(bf_lo(vb.w), wb, acc[6]); acc[7] = fmaf(bf_hi(vb.w), wb, acc[7]);
            }
            if (k + 16 < cnt) {
                const int ic = k + 16 + sub;
                int   sc  = __shfl(s, ic, 64);
                float wc0 = __shfl(w0, ic, 64);
                float wc1 = __shfl(w1, ic, 64);
                float wc = (li < 4) ? wc0 : wc1;
                uint4 vc = *(const uint4*)&xl[(size_t)sc * 64 + li * 8];
                acc[0] = fmaf(bf_lo(vc.x), wc, acc[0]); acc[1] = fmaf(bf_hi(vc.x), wc, acc[1]);
                acc[2] = fmaf(bf_lo(vc.y), wc, acc[2]); acc[3] = fmaf(bf_hi(vc.y), wc, acc[3]);
                acc[4] = fmaf(bf_lo(vc.z), wc, acc[4]); acc[5] = fmaf(bf_hi(vc.z), wc, acc[5]);
                acc[6] = fmaf(bf_lo(vc.w), wc, acc[6]); acc[7] = fmaf(bf_hi(vc.w), wc, acc[7]);
            }
            if (k + 24 < cnt) {
                const int id = k + 24 + sub;
                int   sd  = __shfl(s, id, 64);
                float wd0 = __shfl(w0, id, 64);
                float wd1 = __shfl(w1, id, 64);
                float wd = (li < 4) ? wd0 : wd1;
                uint4 vd = *(const uint4*)&xl[(size_t)sd * 64 + li * 8];
                acc[0] = fmaf(bf_lo(vd.x), wd, acc[0]); acc[1] = fmaf(bf_hi(vd.x), wd, acc[1]);
                acc[2] = fmaf(bf_lo(vd.y), wd, acc[2]); acc[3] = fmaf(bf_hi(vd.y), wd, acc[3]);
                acc[4] = fmaf(bf_lo(vd.z), wd, acc[4]); acc[5] = fmaf(bf_hi(vd.z), wd, acc[5]);
                acc[6] = fmaf(bf_lo(vd.w), wd, acc[6]); acc[7] = fmaf(bf_hi(vd.w), wd, acc[7]);
            }
        }
    }
    #pragma unroll
    for (int ofs = 32; ofs >= 1; ofs >>= 1) {
        ws0 += __shfl_xor(ws0, ofs, 64);
        ws1 += __shfl_xor(ws1, ofs, 64);
    }
    #pragma unroll
    for (int ofs = 8; ofs <= 32; ofs <<= 1) {
        #pragma unroll
        for (int i = 0; i < 8; ++i) acc[i] += __shfl_xor(acc[i], ofs, 64);
    }
    if (sub == 0) {
        const float inv = 1.f / ((li < 4) ? ws0 : ws1);
        float h0 = elu_f(acc[0] * inv + b1a.x);
        float h1 = elu_f(acc[1] * inv + b1a.y);
        float h2 = elu_f(acc[2] * inv + b1a.z);
        float h3 = elu_f(acc[3] * inv + b1a.w);
        float h4 = elu_f(acc[4] * inv + b1b.x);
        float h5 = elu_f(acc[5] * inv + b1b.y);
        float h6 = elu_f(acc[6] * inv + b1b.z);
        float h7 = elu_f(acc[7] * inv + b1b.w);
        uint4 p;
        p.x = (unsigned)f2bf(h0) | ((unsigned)f2bf(h1) << 16);
        p.y = (unsigned)f2bf(h2) | ((unsigned)f2bf(h3) << 16);
        p.z = (unsigned)f2bf(h4) | ((unsigned)f2bf(h5) << 16);
        p.w = (unsigned)f2bf(h6) | ((unsigned)f2bf(h7) << 16);
        *(uint4*)&hout[(size_t)dst * 64 + li * 8] = p;
    }
}

// ---------------- GEMM2 via MFMA: xl2(fp8) = h @ W2, fused attention dots ----
__global__ __launch_bounds__(256) void k_gemm2m(
    const unsigned short* __restrict__ h, const float* __restrict__ W2,
    const float* __restrict__ att_s, const float* __restrict__ att_d,
    unsigned char* __restrict__ xl2, float* __restrict__ a_s, float* __restrict__ a_d)
{
    __shared__ unsigned short W2T[128][72];  // W2^T bf16, pad 72 (18.4 KB)
    __shared__ float psA[4][16], psD[4][16];
    const int t = threadIdx.x, wave = t >> 6, lane = t & 63;
    const int quad = lane >> 4, lm = lane & 15;
    for (int i = t; i < 64 * 128; i += 256)
        W2T[i & 127][i >> 7] = f2bf(W2[i]);  // W2T[c][k] = W2[k][c]
    __syncthreads();

    const int c0 = wave * 32 + lm;
    const int c1 = c0 + 16;
    bf16x8 bfr0[2], bfr1[2];
    #pragma unroll
    for (int s = 0; s < 2; ++s) {
        bfr0[s] = *(const bf16x8*)&W2T[c0][s * 32 + quad * 8];
        bfr1[s] = *(const bf16x8*)&W2T[c1][s * 32 + quad * 8];
    }
    const float as0 = att_s[c0], as1 = att_s[c1];
    const float ad0 = att_d[c0], ad1 = att_d[c1];

    const int r0 = blockIdx.x * 16;
    f32x4 acc0 = {0.f, 0.f, 0.f, 0.f}, acc1 = {0.f, 0.f, 0.f, 0.f};
    #pragma unroll
    for (int s = 0; s < 2; ++s) {
        bf16x8 afr = *(const bf16x8*)&h[(size_t)(r0 + lm) * 64 + s * 32 + quad * 8];
        acc0 = __builtin_amdgcn_mfma_f32_16x16x32_bf16(afr, bfr0[s], acc0, 0, 0, 0);
        acc1 = __builtin_amdgcn_mfma_f32_16x16x32_bf16(afr, bfr1[s], acc1, 0, 0, 0);
    }
    float psv[4], pdv[4];
    #pragma unroll
    for (int r = 0; r < 4; ++r) {
        float v0 = acc0[r], v1 = acc1[r];
        const size_t row = (size_t)(r0 + quad * 4 + r) * 128;
        xl2[row + c0] = f2fp8(v0);          // fp8 e4m3 gather table
        xl2[row + c1] = f2fp8(v1);
        psv[r] = v0 * as0 + v1 * as1;       // logits from fp32 (pre-quant)
        pdv[r] = v0 * ad0 + v1 * ad1;
    }
    #pragma unroll
    for (int ofs = 1; ofs <= 8; ofs <<= 1) {
        #pragma unroll
        for (int r = 0; r < 4; ++r) {
            psv[r] += __shfl_xor(psv[r], ofs, 64);
            pdv[r] += __shfl_xor(pdv[r], ofs, 64);
        }
    }
    if (lm == 0) {
        #pragma unroll
        for (int r = 0; r < 4; ++r) {
            psA[wave][quad * 4 + r] = psv[r];
            psD[wave][quad * 4 + r] = pdv[r];
        }
    }
    __syncthreads();
    if (t < 16) {
        a_s[r0 + t] = psA[0][t] + psA[1][t] + psA[2][t] + psA[3][t];
        a_d[r0 + t] = psD[0][t] + psD[1][t] + psD[2][t] + psD[3][t];
    }
}

// ------- layer-2 attention: fp8 gather, 8 lanes/edge x 16ch, 2x8 edges/iter --
__global__ __launch_bounds__(256) void k_attn2(
    const int* __restrict__ beg_a, const int* __restrict__ end_a,
    const unsigned* __restrict__ csr,
    const float* __restrict__ a_s, const float* __restrict__ a_d,
    const unsigned char* __restrict__ xl, float* __restrict__ out)
{
    const int wave = threadIdx.x >> 6, lane = threadIdx.x & 63;
    const int dst = blockIdx.x * 4 + wave;
    const int beg = beg_a[dst], end = end_a[dst];
    const float ad0 = a_d[dst];

    const int li = lane & 7, sub = lane >> 3;   // ch group li*16..+15; edge slot
    float acc[16];
    #pragma unroll
    for (int i = 0; i < 16; ++i) acc[i] = 0.f;
    float ws0 = 0.f;
    for (int base = beg; base < end; base += 64) {
        const int cnt = min(64, end - base);   // wave-uniform
        int s = 0; float w0 = 0.f;
        if (base + lane < end) {
            s = (int)csr[base + lane];
            float e0 = a_s[s] + ad0; e0 = e0 > 0.f ? e0 : NEG_SLOPE * e0;
            w0 = __expf(e0);
        }
        ws0 += w0;
        for (int k = 0; k < cnt; k += 16) {
            {
                const int ia = k + sub;
                int   sa = __shfl(s, ia, 64);
                float wa = __shfl(w0, ia, 64);
                uint4 va = *(const uint4*)&xl[(size_t)sa * 128 + li * 16];
                f32x2 p;
                p = __builtin_amdgcn_cvt_pk_f32_fp8(va.x, false); acc[0]  = fmaf(p.x, wa, acc[0]);  acc[1]  = fmaf(p.y, wa, acc[1]);
                p = __builtin_amdgcn_cvt_pk_f32_fp8(va.x, true);  acc[2]  = fmaf(p.x, wa, acc[2]);  acc[3]  = fmaf(p.y, wa, acc[3]);
                p = __builtin_amdgcn_cvt_pk_f32_fp8(va.y, false); acc[4]  = fmaf(p.x, wa, acc[4]);  acc[5]  = fmaf(p.y, wa, acc[5]);
                p = __builtin_amdgcn_cvt_pk_f32_fp8(va.y, true);  acc[6]  = fmaf(p.x, wa, acc[6]);  acc[7]  = fmaf(p.y, wa, acc[7]);
                p = __builtin_amdgcn_cvt_pk_f32_fp8(va.z, false); acc[8]  = fmaf(p.x, wa, acc[8]);  acc[9]  = fmaf(p.y, wa, acc[9]);
                p = __builtin_amdgcn_cvt_pk_f32_fp8(va.z, true);  acc[10] = fmaf(p.x, wa, acc[10]); acc[11] = fmaf(p.y, wa, acc[11]);
                p = __builtin_amdgcn_cvt_pk_f32_fp8(va.w, false); acc[12] = fmaf(p.x, wa, acc[12]); acc[13] = fmaf(p.y, wa, acc[13]);
                p = __builtin_amdgcn_cvt_pk_f32_fp8(va.w, true);  acc[14] = fmaf(p.x, wa, acc[14]); acc[15] = fmaf(p.y, wa, acc[15]);
            }
            if (k + 8 < cnt) {      // wave-uniform guard
                const int ib = k + 8 + sub;
                int   sb = __shfl(s, ib, 64);
                float wb = __shfl(w0, ib, 64);
                uint4 vb = *(const uint4*)&xl[(size_t)sb * 128 + li * 16];
                f32x2 p;
                p = __builtin_amdgcn_cvt_pk_f32_fp8(vb.x, false); acc[0]  = fmaf(p.x, wb, acc[0]);  acc[1]  = fmaf(p.y, wb, acc[1]);
                p = __builtin_amdgcn_cvt_pk_f32_fp8(vb.x, true);  acc[2]  = fmaf(p.x, wb, acc[2]);  acc[3]  = fmaf(p.y, wb, acc[3]);
                p = __builtin_amdgcn_cvt_pk_f32_fp8(vb.y, false); acc[4]  = fmaf(p.x, wb, acc[4]);  acc[5]  = fmaf(p.y, wb, acc[5]);
                p = __builtin_amdgcn_cvt_pk_f32_fp8(vb.y, true);  acc[6]  = fmaf(p.x, wb, acc[6]);  acc[7]  = fmaf(p.y, wb, acc[7]);
                p = __builtin_amdgcn_cvt_pk_f32_fp8(vb.z, false); acc[8]  = fmaf(p.x, wb, acc[8]);  acc[9]  = fmaf(p.y, wb, acc[9]);
                p = __builtin_amdgcn_cvt_pk_f32_fp8(vb.z, true);  acc[10] = fmaf(p.x, wb, acc[10]); acc[11] = fmaf(p.y, wb, acc[11]);
                p = __builtin_amdgcn_cvt_pk_f32_fp8(vb.w, false); acc[12] = fmaf(p.x, wb, acc[12]); acc[13] = fmaf(p.y, wb, acc[13]);
                p = __builtin_amdgcn_cvt_pk_f32_fp8(vb.w, true);  acc[14] = fmaf(p.x, wb, acc[14]); acc[15] = fmaf(p.y, wb, acc[15]);
            }
        }
    }
    #pragma unroll
    for (int ofs = 32; ofs >= 1; ofs >>= 1)
        ws0 += __shfl_xor(ws0, ofs, 64);
    #pragma unroll
    for (int ofs = 8; ofs <= 32; ofs <<= 1) {
        #pragma unroll
        for (int i = 0; i < 16; ++i) acc[i] += __shfl_xor(acc[i], ofs, 64);
    }
    if (lane < 8) {
        const float inv = 1.f / ws0;
        float* op = &out[(size_t)dst * 128 + li * 16];
        #pragma unroll
        for (int q = 0; q < 4; ++q) {
            float4 r;
            r.x = acc[q*4+0] * inv; r.y = acc[q*4+1] * inv;
            r.z = acc[q*4+2] * inv; r.w = acc[q*4+3] * inv;
            *(float4*)(op + q * 4) = r;
        }
    }
}

// ---------------- pooling: 32 nodes/block, 2 node-lanes x 128 ch -------------
__global__ __launch_bounds__(256) void k_pool(
    const float* __restrict__ out2, const float* __restrict__ b2,
    const int* __restrict__ batch, float* __restrict__ sums, float* __restrict__ cnts)
{
    const int c    = threadIdx.x & 127;
    const int half = threadIdx.x >> 7;
    const int n0   = blockIdx.x * PN;
    const int nb   = n0 + half;
    if (nb >= N_NODES) return;
    const float bc = b2[c];
    float acc = 0.f;
    int cur = batch[nb], cnt = 0;
    for (int i = half; i < PN; i += 2) {
        int n = n0 + i;
        if (n >= N_NODES) break;
        int g = batch[n];
        if (g != cur) {
            atomicAdd(&sums[cur * OUT_CH + c], acc);
            if (c == 0) atomicAdd(&cnts[cur], (float)cnt);
            acc = 0.f; cnt = 0; cur = g;
        }
        acc += elu_f(out2[(size_t)n * OUT_CH + c] + bc);
        cnt++;
    }
    if (cnt > 0) {
        atomicAdd(&sums[cur * OUT_CH + c], acc);
        if (c == 0) atomicAdd(&cnts[cur], (float)cnt);
    }
}

__global__ __launch_bounds__(256) void k_final(
    const float* __restrict__ sums, const float* __restrict__ cnts,
    float* __restrict__ out)
{
    int i = blockIdx.x * 256 + threadIdx.x;
    if (i >= N_GRAPHS * OUT_CH) return;
    out[i] = sums[i] / fmaxf(cnts[i >> 7], 1.f);
}

extern "C" void kernel_launch(void* const* d_in, const int* in_sizes, int n_in,
                              void* d_out, int out_size, void* d_ws, size_t ws_size,
                              hipStream_t stream)
{
    const float* x    = (const float*)d_in[0];
    const int*   ei   = (const int*)d_in[1];
    const int*   batch= (const int*)d_in[2];
    const float* W1   = (const float*)d_in[3];
    const float* as1  = (const float*)d_in[4];
    const float* ad1  = (const float*)d_in[5];
    const float* b1   = (const float*)d_in[6];
    const float* W2   = (const float*)d_in[7];
    const float* as2  = (const float*)d_in[8];
    const float* ad2  = (const float*)d_in[9];
    const float* b2   = (const float*)d_in[10];

    float* ws = (float*)d_ws;
    size_t o = 0;
    unsigned short* xl1b = (unsigned short*)(ws + o); o += (size_t)N_NODES * C1 / 2;
    unsigned short* hbuf = (unsigned short*)(ws + o); o += (size_t)N_NODES * C1 / 2;
    unsigned char*  xl2q = (unsigned char*)(ws + o);  o += (size_t)N_NODES * OUT_CH / 4;
    float*    a_s1 = ws + o; o += (size_t)N_NODES * 2;
    float*    a_d1 = ws + o; o += (size_t)N_NODES * 2;
    float*    a_s2 = ws + o; o += (size_t)N_NODES;
    float*    a_d2 = ws + o; o += (size_t)N_NODES;
    float*    out2 = ws + o; o += (size_t)N_NODES * OUT_CH;
    unsigned* bbuf = (unsigned*)(ws + o); o += (size_t)NBUCK * BCAP;
    int*      beg  = (int*)(ws + o); o += (size_t)N_NODES;
    int*      end  = (int*)(ws + o); o += (size_t)N_NODES;
    size_t zero_start = o;
    int*      gcur = (int*)(ws + o); o += (size_t)NBUCK;
    float*    sums = ws + o;         o += (size_t)N_GRAPHS * OUT_CH;
    float*    cnts = ws + o;         o += (size_t)N_GRAPHS;
    size_t zero_bytes = (o - zero_start) * sizeof(float);
    hipMemsetAsync(ws + zero_start, 0, zero_bytes, stream);

    const int nchunks = (E_TOT + CHUNK - 1) / CHUNK;   // 202
    k_bin<<<nchunks, 256, 0, stream>>>(ei, gcur, bbuf);
    k_bsort<<<NBUCK, 256, 0, stream>>>(gcur, bbuf, beg, end);

    k_gemm1<<<N_NODES / 16, 256, 0, stream>>>(x, W1, as1, ad1, xl1b, a_s1, a_d1);
    k_attn1<<<N_NODES / 4, 256, 0, stream>>>(beg, end, bbuf, a_s1, a_d1, xl1b, b1, hbuf);
    k_gemm2m<<<(N_NODES + 15) / 16, 256, 0, stream>>>(hbuf, W2, as2, ad2, xl2q, a_s2, a_d2);
    k_attn2<<<N_NODES / 4, 256, 0, stream>>>(beg, end, bbuf, a_s2, a_d2, xl2q, out2);
    k_pool<<<(N_NODES + PN - 1) / PN, 256, 0, stream>>>(out2, b2, batch, sums, cnts);
    k_final<<<(N_GRAPHS * OUT_CH + 255) / 256, 256, 0, stream>>>(sums, cnts, (float*)d_out);
}